// Round 7
// baseline (482.274 us; speedup 1.0000x reference)
//
#include <hip/hip_runtime.h>
#include <stdint.h>

#define Bb 4
#define Tt 2048
#define Dd 1024
#define Hh 16
#define HDd 64
#define Mm 8192   // Bb*Tt

typedef __attribute__((ext_vector_type(8))) short bf16x8;
typedef __attribute__((ext_vector_type(4))) float f32x4;
typedef __attribute__((ext_vector_type(16))) float f32x16;

#define MFMA(a, b, c) __builtin_amdgcn_mfma_f32_16x16x32_bf16(a, b, c, 0, 0, 0)
#define MFMA32(a, b, c) __builtin_amdgcn_mfma_f32_32x32x16_bf16(a, b, c, 0, 0, 0)

#define LOG2E 1.44269504088896340736f
#if __has_builtin(__builtin_amdgcn_exp2f)
#define EXP2(x) __builtin_amdgcn_exp2f(x)
#else
#define EXP2(x) __expf((x) * 0.69314718055994530942f)
#endif

union vfu { uint2 u2[2]; bf16x8 v; };
union apu { uint32_t u[4]; bf16x8 v; };

__device__ __forceinline__ unsigned short f2b(float f) {
  union { float f; uint32_t u; } v; v.f = f;
  return (unsigned short)((v.u + 0x7FFFu + ((v.u >> 16) & 1u)) >> 16);
}

// pack two f32 -> bf16x2 (compiler emits v_cvt_pk_bf16_f32)
__device__ __forceinline__ uint32_t pk2(float a, float b) {
  union { __bf16 h[2]; uint32_t u; } x;
  x.h[0] = (__bf16)a; x.h[1] = (__bf16)b;
  return x.u;
}

__device__ __forceinline__ void gload_lds16(const void* g, void* l) {
  __builtin_amdgcn_global_load_lds(
      (const __attribute__((address_space(1))) void*)g,
      (__attribute__((address_space(3))) void*)l, 16, 0, 0);
}

// ---------------- x f32 -> bf16 ----------------
__global__ __launch_bounds__(256) void k_convert_x(const float* __restrict__ x,
                                                   unsigned short* __restrict__ xb) {
  int i = (blockIdx.x * 256 + threadIdx.x) * 8;
  float4 a = *(const float4*)(x + i);
  float4 b = *(const float4*)(x + i + 4);
  uint4 o;
  o.x = f2b(a.x) | ((uint32_t)f2b(a.y) << 16);
  o.y = f2b(a.z) | ((uint32_t)f2b(a.w) << 16);
  o.z = f2b(b.x) | ((uint32_t)f2b(b.y) << 16);
  o.w = f2b(b.z) | ((uint32_t)f2b(b.w) << 16);
  *(uint4*)(xb + i) = o;
}

// ---------------- W [K][N] f32 -> Wt [N][K] bf16 ----------------
__global__ __launch_bounds__(256) void k_transpose_w(
    const float* __restrict__ Wk, const float* __restrict__ Wq,
    const float* __restrict__ Wv, const float* __restrict__ Wp,
    unsigned short* __restrict__ WkT, unsigned short* __restrict__ WqT,
    unsigned short* __restrict__ WvT, unsigned short* __restrict__ WpT) {
  const float* W; unsigned short* O;
  int wsel = blockIdx.y;
  W = wsel == 0 ? Wk : wsel == 1 ? Wq : wsel == 2 ? Wv : Wp;
  O = wsel == 0 ? WkT : wsel == 1 ? WqT : wsel == 2 ? WvT : WpT;
  __shared__ unsigned short tile[32][36];
  int kb = (blockIdx.x >> 5) << 5;
  int nb = (blockIdx.x & 31) << 5;
  int t = threadIdx.x;
  int r = t >> 3, c4 = (t & 7) << 2;
  float4 v = *(const float4*)(W + (size_t)(kb + r) * Dd + nb + c4);
  tile[r][c4 + 0] = f2b(v.x); tile[r][c4 + 1] = f2b(v.y);
  tile[r][c4 + 2] = f2b(v.z); tile[r][c4 + 3] = f2b(v.w);
  __syncthreads();
  uint2 o;
  o.x = tile[c4 + 0][r] | ((uint32_t)tile[c4 + 1][r] << 16);
  o.y = tile[c4 + 2][r] | ((uint32_t)tile[c4 + 3][r] << 16);
  *(uint2*)(O + (size_t)(nb + r) * Dd + kb + c4) = o;
}

// ---------------- GEMM: A[M][1024] bf16 @ Bt[N][1024]^T + bias ----------------
// qkv=1: Q,K -> [B,H,T,64] (Q pre-scaled by 0.125*log2e), V -> [B,H,64,T]
// qkv=0: f32 out [M][1024]
__global__ __launch_bounds__(256) void k_gemm(
    const unsigned short* __restrict__ A,
    const unsigned short* __restrict__ Bt0, const unsigned short* __restrict__ Bt1,
    const unsigned short* __restrict__ Bt2,
    const float* __restrict__ bias0, const float* __restrict__ bias1,
    const float* __restrict__ bias2,
    unsigned short* __restrict__ Qb, unsigned short* __restrict__ Kb,
    unsigned short* __restrict__ VTb, float* __restrict__ Pout, int qkv) {
  __shared__ __align__(16) unsigned short Al[128 * 32];
  __shared__ __align__(16) unsigned short Bl[128 * 32];
  int tid = threadIdx.x;
  int lane = tid & 63, wid = tid >> 6;
  int wr = wid >> 1, wc = wid & 1;
  int lq = lane & 15, lh = lane >> 4;
  int mb = blockIdx.x * 128;
  int by = blockIdx.y;
  int widx, nb;
  const unsigned short* Bt; const float* bias;
  if (qkv) {
    widx = by >> 3; nb = (by & 7) << 7;
    Bt = widx == 0 ? Bt0 : (widx == 1 ? Bt1 : Bt2);
    bias = widx == 0 ? bias0 : (widx == 1 ? bias1 : bias2);
  } else {
    widx = 3; nb = by << 7; Bt = Bt0; bias = bias0;
  }

  int srow = (wid << 5) + (lane >> 2);
  int scol = (lane & 3) << 3;
  const unsigned short* Ag = A + (size_t)(mb + srow) * Dd + scol;
  const unsigned short* Bg = Bt + (size_t)(nb + srow) * Dd + scol;
  unsigned short* Alw = Al + (wid << 10);
  unsigned short* Blw = Bl + (wid << 10);

  f32x4 zero = {0.f, 0.f, 0.f, 0.f};
  f32x4 acc[4][4];
#pragma unroll
  for (int m = 0; m < 4; m++)
#pragma unroll
    for (int n = 0; n < 4; n++) acc[m][n] = zero;

  for (int kb = 0; kb < Dd; kb += 32) {
    __syncthreads();
    gload_lds16(Ag + kb, Alw);
    gload_lds16(Ag + kb + 16 * Dd, Alw + 16 * 32);
    gload_lds16(Bg + kb, Blw);
    gload_lds16(Bg + kb + 16 * Dd, Blw + 16 * 32);
    __syncthreads();
    bf16x8 af[4], bf[4];
#pragma unroll
    for (int m = 0; m < 4; m++)
      af[m] = *(const bf16x8*)(Al + (((wr << 6) + (m << 4) + lq) << 5) + (lh << 3));
#pragma unroll
    for (int n = 0; n < 4; n++)
      bf[n] = *(const bf16x8*)(Bl + (((wc << 6) + (n << 4) + lq) << 5) + (lh << 3));
#pragma unroll
    for (int m = 0; m < 4; m++)
#pragma unroll
      for (int n = 0; n < 4; n++) acc[m][n] = MFMA(af[m], bf[n], acc[m][n]);
  }

  int b_idx = mb >> 11;
#pragma unroll
  for (int n = 0; n < 4; n++) {
    int col = nb + (wc << 6) + (n << 4) + lq;
    float bb = bias[col];
    int hh = col >> 6, hd = col & 63;
#pragma unroll
    for (int m = 0; m < 4; m++) {
      int row0 = mb + (wr << 6) + (m << 4) + (lh << 2);
      int t0 = row0 & 2047;
      if (widx == 3) {
#pragma unroll
        for (int r = 0; r < 4; r++)
          Pout[(size_t)(row0 + r) * Dd + col] = acc[m][n][r] + bb;
      } else if (widx == 2) {
        float v0 = acc[m][n][0] + bb, v1 = acc[m][n][1] + bb;
        float v2 = acc[m][n][2] + bb, v3 = acc[m][n][3] + bb;
        uint2 pv;
        pv.x = f2b(v0) | ((uint32_t)f2b(v1) << 16);
        pv.y = f2b(v2) | ((uint32_t)f2b(v3) << 16);
        *(uint2*)(VTb + ((size_t)(b_idx * 16 + hh) * 64 + hd) * Tt + t0) = pv;
      } else {
        unsigned short* O = (widx == 0) ? Qb : Kb;
        float sc = (widx == 0) ? (0.125f * LOG2E) : 1.0f;  // fold scale*log2e into Q
#pragma unroll
        for (int r = 0; r < 4; r++) {
          float v = (acc[m][n][r] + bb) * sc;
          O[((size_t)(b_idx * 16 + hh) * Tt + (t0 + r)) * 64 + hd] = f2b(v);
        }
      }
    }
  }
}

// ---------------- flash attention (causal), Q pre-scaled by 0.125*log2e ----------
// NO LDS, NO barriers: each wave owns 32 q rows and reads K/V fragments
// directly from global (K/V per head = 512 KB, L2-resident; XCD-chunked so a
// head's blocks share one XCD L2). Swapped QK^T (mfma(K,Q)), register-local
// P pack (validated r5/r6), manual 2-stage K prefetch. Waves fully independent.

#define KLOAD(KF, jt_) do {                                                     \
    const unsigned short* kp_ = Kh + ((size_t)((jt_) << 5) + l31) * 64 + (hi << 3); \
    KF[0] = *(const bf16x8*)(kp_);                                              \
    KF[1] = *(const bf16x8*)(kp_ + 16);                                         \
    KF[2] = *(const bf16x8*)(kp_ + 32);                                         \
    KF[3] = *(const bf16x8*)(kp_ + 48);                                         \
  } while (0)

#define ATTN_TILE(KF, jt_, DIAG) do {                                           \
    int kv0_ = (jt_) << 5;                                                      \
    vfu vf_[2][2];                                                              \
    _Pragma("unroll")                                                           \
    for (int n2v_ = 0; n2v_ < 2; n2v_++) {                                      \
      const unsigned short* vp_ =                                               \
          Vh + (size_t)((n2v_ << 5) + l31) * Tt + kv0_ + (hi << 2);             \
      vf_[n2v_][0].u2[0] = *(const uint2*)(vp_);                                \
      vf_[n2v_][0].u2[1] = *(const uint2*)(vp_ + 8);                            \
      vf_[n2v_][1].u2[0] = *(const uint2*)(vp_ + 16);                           \
      vf_[n2v_][1].u2[1] = *(const uint2*)(vp_ + 24);                           \
    }                                                                           \
    f32x16 s_;                                                                  \
    _Pragma("unroll")                                                           \
    for (int i_ = 0; i_ < 16; i_++) s_[i_] = 0.f;                               \
    _Pragma("unroll")                                                           \
    for (int c_ = 0; c_ < 4; c_++) s_ = MFMA32(KF[c_], qf[c_], s_);             \
    float p_[16];                                                               \
    if (DIAG) {                                                                 \
      _Pragma("unroll")                                                         \
      for (int r_ = 0; r_ < 16; r_++) {                                         \
        int krow_ = (r_ & 3) + ((r_ >> 2) << 3) + (hi << 2);                    \
        p_[r_] = EXP2(krow_ > l31 ? -1e30f : s_[r_]);                           \
      }                                                                         \
    } else {                                                                    \
      _Pragma("unroll")                                                         \
      for (int r_ = 0; r_ < 16; r_++) p_[r_] = EXP2(s_[r_]);                    \
    }                                                                           \
    lsum += (((p_[0] + p_[1]) + (p_[2] + p_[3])) +                              \
             ((p_[4] + p_[5]) + (p_[6] + p_[7]))) +                             \
            (((p_[8] + p_[9]) + (p_[10] + p_[11])) +                            \
             ((p_[12] + p_[13]) + (p_[14] + p_[15])));                          \
    apu ap0_, ap1_;                                                             \
    _Pragma("unroll")                                                           \
    for (int g_ = 0; g_ < 4; g_++) {                                            \
      ap0_.u[g_] = pk2(p_[2 * g_], p_[2 * g_ + 1]);                             \
      ap1_.u[g_] = pk2(p_[8 + 2 * g_], p_[8 + 2 * g_ + 1]);                     \
    }                                                                           \
    acc0 = MFMA32(ap0_.v, vf_[0][0].v, acc0);                                   \
    acc1 = MFMA32(ap0_.v, vf_[1][0].v, acc1);                                   \
    acc0 = MFMA32(ap1_.v, vf_[0][1].v, acc0);                                   \
    acc1 = MFMA32(ap1_.v, vf_[1][1].v, acc1);                                   \
  } while (0)

__global__ __launch_bounds__(256, 4) void k_attn(
    const unsigned short* __restrict__ Qb, const unsigned short* __restrict__ Kb,
    const unsigned short* __restrict__ VTb, unsigned short* __restrict__ yb) {
  int raw = blockIdx.x;
  int blk = ((raw & 7) << 7) | (raw >> 3);   // XCD chunk: 8 heads per XCD
  int bh = blk >> 4;
  int qb = 15 - (blk & 15);                  // heavy q-blocks first
  int tid = threadIdx.x, lane = tid & 63, w = tid >> 6;
  int l31 = lane & 31, hi = lane >> 5;
  const unsigned short* __restrict__ Qh = Qb + (size_t)bh * Tt * 64;
  const unsigned short* __restrict__ Kh = Kb + (size_t)bh * Tt * 64;
  const unsigned short* __restrict__ Vh = VTb + (size_t)bh * 64 * Tt;
  int qg = (qb << 7) + (w << 5);             // wave's 32 q rows

  // Q B-fragments: lane holds Q[qg+l31][16c + 8hi + j]
  bf16x8 qf[4];
#pragma unroll
  for (int c = 0; c < 4; c++)
    qf[c] = *(const bf16x8*)(Qh + (size_t)(qg + l31) * 64 + (c << 4) + (hi << 3));

  f32x16 acc0, acc1;
#pragma unroll
  for (int i = 0; i < 16; i++) { acc0[i] = 0.f; acc1[i] = 0.f; }
  float lsum = 0.f;

  int jmax = qg >> 5;      // kv tiles of 32 rows: 0..jmax (jmax = diagonal)
  bf16x8 kfA[4], kfB[4];
  KLOAD(kfA, 0);
  int jt = 0;
  while (jt < jmax) {
    KLOAD(kfB, jt + 1);
    ATTN_TILE(kfA, jt, false);
    ++jt;
    if (jt < jmax) {
      KLOAD(kfA, jt + 1);
      ATTN_TILE(kfB, jt, false);
      ++jt;
    } else {
      ATTN_TILE(kfB, jt, true);
      ++jt;
    }
  }
  if (jt == jmax) ATTN_TILE(kfA, jt, true);

  lsum += __shfl_xor(lsum, 32);
  float inv = 1.0f / lsum;
  int bb = bh >> 4, hh = bh & 15;
#pragma unroll
  for (int r = 0; r < 16; r++) {
    int qr = (r & 3) + ((r >> 2) << 3) + (hi << 2);
    float invq = __shfl(inv, qr);
    size_t base = ((size_t)(bb * Tt + qg + qr)) * Dd + (hh << 6) + l31;
    yb[base] = f2b(acc0[r] * invq);
    yb[base + 32] = f2b(acc1[r] * invq);
  }
}

extern "C" void kernel_launch(void* const* d_in, const int* in_sizes, int n_in,
                              void* d_out, int out_size, void* d_ws, size_t ws_size,
                              hipStream_t stream) {
  const float* x = (const float*)d_in[0];
  const float* Wk = (const float*)d_in[1];
  const float* bk = (const float*)d_in[2];
  const float* Wq = (const float*)d_in[3];
  const float* bq = (const float*)d_in[4];
  const float* Wv = (const float*)d_in[5];
  const float* bv = (const float*)d_in[6];
  const float* Wp = (const float*)d_in[7];
  const float* bp = (const float*)d_in[8];
  float* out = (float*)d_out;

  char* ws = (char*)d_ws;
  unsigned short* xb  = (unsigned short*)(ws);                       // 16MB
  unsigned short* WkT = (unsigned short*)(ws + (16ull << 20));       // 2MB each
  unsigned short* WqT = (unsigned short*)(ws + (18ull << 20));
  unsigned short* WvT = (unsigned short*)(ws + (20ull << 20));
  unsigned short* WpT = (unsigned short*)(ws + (22ull << 20));
  unsigned short* Qb  = (unsigned short*)(ws + (24ull << 20));       // 16MB
  unsigned short* Kb  = (unsigned short*)(ws + (40ull << 20));       // 16MB
  unsigned short* VTb = (unsigned short*)(ws + (56ull << 20));       // 16MB
  unsigned short* yb  = (unsigned short*)(ws + (72ull << 20));       // 16MB (ends 88MB)

  k_convert_x<<<4096, 256, 0, stream>>>(x, xb);
  k_transpose_w<<<dim3(1024, 4), 256, 0, stream>>>(Wk, Wq, Wv, Wp, WkT, WqT, WvT, WpT);
  k_gemm<<<dim3(64, 24), 256, 0, stream>>>(xb, WqT, WkT, WvT, bq, bk, bv,
                                           Qb, Kb, VTb, nullptr, 1);
  k_attn<<<1024, 256, 0, stream>>>(Qb, Kb, VTb, yb);
  k_gemm<<<dim3(64, 8), 256, 0, stream>>>(yb, WpT, nullptr, nullptr, bp, nullptr, nullptr,
                                          nullptr, nullptr, nullptr, out, 0);
}

// Round 8
// 311.355 us; speedup vs baseline: 1.5490x; 1.5490x over previous
//
#include <hip/hip_runtime.h>
#include <stdint.h>

#define Bb 4
#define Tt 2048
#define Dd 1024
#define Hh 16
#define HDd 64
#define Mm 8192   // Bb*Tt

typedef __attribute__((ext_vector_type(8))) short bf16x8;
typedef __attribute__((ext_vector_type(4))) float f32x4;
typedef __attribute__((ext_vector_type(16))) float f32x16;

#define MFMA(a, b, c) __builtin_amdgcn_mfma_f32_16x16x32_bf16(a, b, c, 0, 0, 0)
#define MFMA32(a, b, c) __builtin_amdgcn_mfma_f32_32x32x16_bf16(a, b, c, 0, 0, 0)

#define LOG2E 1.44269504088896340736f
#if __has_builtin(__builtin_amdgcn_exp2f)
#define EXP2(x) __builtin_amdgcn_exp2f(x)
#else
#define EXP2(x) __expf((x) * 0.69314718055994530942f)
#endif

union vfu { uint2 u2[2]; bf16x8 v; };
union apu { uint32_t u[4]; bf16x8 v; };

__device__ __forceinline__ unsigned short f2b(float f) {
  union { float f; uint32_t u; } v; v.f = f;
  return (unsigned short)((v.u + 0x7FFFu + ((v.u >> 16) & 1u)) >> 16);
}

// pack two f32 -> bf16x2 (compiler emits v_cvt_pk_bf16_f32)
__device__ __forceinline__ uint32_t pk2(float a, float b) {
  union { __bf16 h[2]; uint32_t u; } x;
  x.h[0] = (__bf16)a; x.h[1] = (__bf16)b;
  return x.u;
}

__device__ __forceinline__ void gload_lds16(const void* g, void* l) {
  __builtin_amdgcn_global_load_lds(
      (const __attribute__((address_space(1))) void*)g,
      (__attribute__((address_space(3))) void*)l, 16, 0, 0);
}

// ---------------- x f32 -> bf16 ----------------
__global__ __launch_bounds__(256) void k_convert_x(const float* __restrict__ x,
                                                   unsigned short* __restrict__ xb) {
  int i = (blockIdx.x * 256 + threadIdx.x) * 8;
  float4 a = *(const float4*)(x + i);
  float4 b = *(const float4*)(x + i + 4);
  uint4 o;
  o.x = f2b(a.x) | ((uint32_t)f2b(a.y) << 16);
  o.y = f2b(a.z) | ((uint32_t)f2b(a.w) << 16);
  o.z = f2b(b.x) | ((uint32_t)f2b(b.y) << 16);
  o.w = f2b(b.z) | ((uint32_t)f2b(b.w) << 16);
  *(uint4*)(xb + i) = o;
}

// ---------------- W [K][N] f32 -> Wt [N][K] bf16 ----------------
__global__ __launch_bounds__(256) void k_transpose_w(
    const float* __restrict__ Wk, const float* __restrict__ Wq,
    const float* __restrict__ Wv, const float* __restrict__ Wp,
    unsigned short* __restrict__ WkT, unsigned short* __restrict__ WqT,
    unsigned short* __restrict__ WvT, unsigned short* __restrict__ WpT) {
  const float* W; unsigned short* O;
  int wsel = blockIdx.y;
  W = wsel == 0 ? Wk : wsel == 1 ? Wq : wsel == 2 ? Wv : Wp;
  O = wsel == 0 ? WkT : wsel == 1 ? WqT : wsel == 2 ? WvT : WpT;
  __shared__ unsigned short tile[32][36];
  int kb = (blockIdx.x >> 5) << 5;
  int nb = (blockIdx.x & 31) << 5;
  int t = threadIdx.x;
  int r = t >> 3, c4 = (t & 7) << 2;
  float4 v = *(const float4*)(W + (size_t)(kb + r) * Dd + nb + c4);
  tile[r][c4 + 0] = f2b(v.x); tile[r][c4 + 1] = f2b(v.y);
  tile[r][c4 + 2] = f2b(v.z); tile[r][c4 + 3] = f2b(v.w);
  __syncthreads();
  uint2 o;
  o.x = tile[c4 + 0][r] | ((uint32_t)tile[c4 + 1][r] << 16);
  o.y = tile[c4 + 2][r] | ((uint32_t)tile[c4 + 3][r] << 16);
  *(uint2*)(O + (size_t)(nb + r) * Dd + kb + c4) = o;
}

// ---------------- GEMM: A[M][1024] bf16 @ Bt[N][1024]^T + bias ----------------
// qkv=1: Q,K -> [B,H,T,64] (K row-swizzled, Q pre-scaled by 0.125*log2e),
//        V -> [B,H,64,T] (t-swizzled)
// qkv=0: f32 out [M][1024]
__global__ __launch_bounds__(256) void k_gemm(
    const unsigned short* __restrict__ A,
    const unsigned short* __restrict__ Bt0, const unsigned short* __restrict__ Bt1,
    const unsigned short* __restrict__ Bt2,
    const float* __restrict__ bias0, const float* __restrict__ bias1,
    const float* __restrict__ bias2,
    unsigned short* __restrict__ Qb, unsigned short* __restrict__ Kb,
    unsigned short* __restrict__ VTb, float* __restrict__ Pout, int qkv) {
  __shared__ __align__(16) unsigned short Al[128 * 32];
  __shared__ __align__(16) unsigned short Bl[128 * 32];
  int tid = threadIdx.x;
  int lane = tid & 63, wid = tid >> 6;
  int wr = wid >> 1, wc = wid & 1;
  int lq = lane & 15, lh = lane >> 4;
  int mb = blockIdx.x * 128;
  int by = blockIdx.y;
  int widx, nb;
  const unsigned short* Bt; const float* bias;
  if (qkv) {
    widx = by >> 3; nb = (by & 7) << 7;
    Bt = widx == 0 ? Bt0 : (widx == 1 ? Bt1 : Bt2);
    bias = widx == 0 ? bias0 : (widx == 1 ? bias1 : bias2);
  } else {
    widx = 3; nb = by << 7; Bt = Bt0; bias = bias0;
  }

  int srow = (wid << 5) + (lane >> 2);
  int scol = (lane & 3) << 3;
  const unsigned short* Ag = A + (size_t)(mb + srow) * Dd + scol;
  const unsigned short* Bg = Bt + (size_t)(nb + srow) * Dd + scol;
  unsigned short* Alw = Al + (wid << 10);
  unsigned short* Blw = Bl + (wid << 10);

  f32x4 zero = {0.f, 0.f, 0.f, 0.f};
  f32x4 acc[4][4];
#pragma unroll
  for (int m = 0; m < 4; m++)
#pragma unroll
    for (int n = 0; n < 4; n++) acc[m][n] = zero;

  for (int kb = 0; kb < Dd; kb += 32) {
    __syncthreads();
    gload_lds16(Ag + kb, Alw);
    gload_lds16(Ag + kb + 16 * Dd, Alw + 16 * 32);
    gload_lds16(Bg + kb, Blw);
    gload_lds16(Bg + kb + 16 * Dd, Blw + 16 * 32);
    __syncthreads();
    bf16x8 af[4], bf[4];
#pragma unroll
    for (int m = 0; m < 4; m++)
      af[m] = *(const bf16x8*)(Al + (((wr << 6) + (m << 4) + lq) << 5) + (lh << 3));
#pragma unroll
    for (int n = 0; n < 4; n++)
      bf[n] = *(const bf16x8*)(Bl + (((wc << 6) + (n << 4) + lq) << 5) + (lh << 3));
#pragma unroll
    for (int m = 0; m < 4; m++)
#pragma unroll
      for (int n = 0; n < 4; n++) acc[m][n] = MFMA(af[m], bf[n], acc[m][n]);
  }

  int b_idx = mb >> 11;
#pragma unroll
  for (int n = 0; n < 4; n++) {
    int col = nb + (wc << 6) + (n << 4) + lq;
    float bb = bias[col];
    int hh = col >> 6, hd = col & 63;
#pragma unroll
    for (int m = 0; m < 4; m++) {
      int row0 = mb + (wr << 6) + (m << 4) + (lh << 2);
      int t0 = row0 & 2047;
      if (widx == 3) {
#pragma unroll
        for (int r = 0; r < 4; r++)
          Pout[(size_t)(row0 + r) * Dd + col] = acc[m][n][r] + bb;
      } else if (widx == 2) {
        float v0 = acc[m][n][0] + bb, v1 = acc[m][n][1] + bb;
        float v2 = acc[m][n][2] + bb, v3 = acc[m][n][3] + bb;
        uint2 pv;
        pv.x = f2b(v0) | ((uint32_t)f2b(v1) << 16);
        pv.y = f2b(v2) | ((uint32_t)f2b(v3) << 16);
        int t0s = t0 ^ ((hd & 7) << 3);  // V swizzle: t 16B-block ^= hd&7
        *(uint2*)(VTb + ((size_t)(b_idx * 16 + hh) * 64 + hd) * Tt + t0s) = pv;
      } else {
        unsigned short* O = (widx == 0) ? Qb : Kb;
        float sc = (widx == 0) ? (0.125f * LOG2E) : 1.0f;  // fold scale*log2e into Q
#pragma unroll
        for (int r = 0; r < 4; r++) {
          float v = (acc[m][n][r] + bb) * sc;
          int trow = t0 + r;
          int hds = (widx == 0) ? hd : (hd ^ ((trow & 7) << 3));  // K swizzle
          O[((size_t)(b_idx * 16 + hh) * Tt + trow) * 64 + hds] = f2b(v);
        }
      }
    }
  }
}

// ---------------- flash attention (causal), Q pre-scaled by 0.125*log2e ----------
// r5 (92us) per-tile math VERBATIM, repackaged: block = 256 thr / 4 waves,
// each wave owns 32 q rows of a 128-row q-tile; grid = 64 bh x 16 q-tiles
// (heavy-first, XCD-chunked). K/V staged via global_load_lds, double buffer,
// early exit at block's own diagonal (jmax = 2*qt+1). 32 KB LDS -> 5 blocks/CU.
__global__ __launch_bounds__(256, 5) void k_attn(
    const unsigned short* __restrict__ Qb, const unsigned short* __restrict__ Kb,
    const unsigned short* __restrict__ VTb, unsigned short* __restrict__ yb) {
  __shared__ __align__(16) unsigned short KL[2][4096];
  __shared__ __align__(16) unsigned short VL[2][4096];
  int raw = blockIdx.x;
  int blk = ((raw & 7) << 7) | (raw >> 3);   // XCD chunk (1024%8==0, bijective)
  int bh = blk >> 4;
  int qt = 15 - (blk & 15);                  // heavy q-tiles first
  int tid = threadIdx.x, lane = tid & 63, w = tid >> 6;
  int l31 = lane & 31, hi = lane >> 5;
  const unsigned short* __restrict__ Qh = Qb + (size_t)bh * Tt * 64;
  const unsigned short* __restrict__ Kh = Kb + (size_t)bh * Tt * 64;
  const unsigned short* __restrict__ Vh = VTb + (size_t)bh * 64 * Tt;
  int qg = (qt << 7) + (w << 5);             // wave's 32 q rows

  // Q B-fragments: lane holds Q[qg+l31][16c + 8hi + j]
  bf16x8 qf[4];
#pragma unroll
  for (int c = 0; c < 4; c++)
    qf[c] = *(const bf16x8*)(Qh + (size_t)(qg + l31) * 64 + (c << 4) + (hi << 3));

  f32x16 acc0, acc1;
#pragma unroll
  for (int i = 0; i < 16; i++) { acc0[i] = 0.f; acc1[i] = 0.f; }
  float lsum = 0.f;

  int jmax = (qt << 1) + 1;    // 64-row kv tiles: 0..jmax covers the q-tile diag
  int srow = lane >> 3, scol = (lane & 7) << 3;
  int rowb = w << 4;           // wave stages 16 rows of K and of V per tile
  int swz = l31 & 7;

  // prologue: stage tile 0 into buf 0
  gload_lds16(Kh + (size_t)(rowb + srow) * 64 + scol, &KL[0][rowb << 6]);
  gload_lds16(Kh + (size_t)(rowb + 8 + srow) * 64 + scol, &KL[0][(rowb + 8) << 6]);
  gload_lds16(Vh + (size_t)(rowb + srow) * Tt + scol, &VL[0][rowb << 6]);
  gload_lds16(Vh + (size_t)(rowb + 8 + srow) * Tt + scol, &VL[0][(rowb + 8) << 6]);
  __syncthreads();

  int cur = 0;
  for (int jt = 0; jt <= jmax; ++jt) {
    if (jt < jmax) {  // stage next tile into the other buffer (hides under compute)
      int kv1 = (jt + 1) << 6;
      gload_lds16(Kh + (size_t)(kv1 + rowb + srow) * 64 + scol, &KL[cur ^ 1][rowb << 6]);
      gload_lds16(Kh + (size_t)(kv1 + rowb + 8 + srow) * 64 + scol,
                  &KL[cur ^ 1][(rowb + 8) << 6]);
      gload_lds16(Vh + (size_t)(rowb + srow) * Tt + kv1 + scol, &VL[cur ^ 1][rowb << 6]);
      gload_lds16(Vh + (size_t)(rowb + 8 + srow) * Tt + kv1 + scol,
                  &VL[cur ^ 1][(rowb + 8) << 6]);
    }
    int kv0 = jt << 6;
    int d = qg - kv0;   // wave-uniform
    if (d >= 0) {
      const unsigned short* KB = &KL[cur][0];
      const unsigned short* VB = &VL[cur][0];
      bool diag = (d < 64);
      int rel = d + l31;
#pragma unroll
      for (int n2 = 0; n2 < 2; n2++) {
        // K fragments for this kv-half
        bf16x8 kf[4];
        int krowb = ((n2 << 5) + l31) << 6;
#pragma unroll
        for (int c = 0; c < 4; c++)
          kf[c] = *(const bf16x8*)(KB + krowb + ((((c << 1) + hi) ^ swz) << 3));
        f32x16 s;
#pragma unroll
        for (int i = 0; i < 16; i++) s[i] = 0.f;
        __builtin_amdgcn_s_setprio(1);
#pragma unroll
        for (int c = 0; c < 4; c++) s = MFMA32(kf[c], qf[c], s);
        __builtin_amdgcn_s_setprio(0);
        float p[16];
        if (diag) {
#pragma unroll
          for (int r = 0; r < 16; r++) {
            int krow = (n2 << 5) + (r & 3) + ((r >> 2) << 3) + (hi << 2);
            p[r] = EXP2(krow > rel ? -1e30f : s[r]);
          }
        } else {
#pragma unroll
          for (int r = 0; r < 16; r++) p[r] = EXP2(s[r]);
        }
        lsum += (((p[0] + p[1]) + (p[2] + p[3])) + ((p[4] + p[5]) + (p[6] + p[7])))
              + (((p[8] + p[9]) + (p[10] + p[11])) + ((p[12] + p[13]) + (p[14] + p[15])));
        // V fragments: element (hi,j) = V[kv0 + 32n2 + 16cc + 8(j>>2)+4hi+(j&3)][hd]
        union { uint2 u2[2]; bf16x8 v; } vf[2][2];
#pragma unroll
        for (int n2v = 0; n2v < 2; n2v++) {
          int vrowb = ((n2v << 5) + l31) << 6;
#pragma unroll
          for (int cc = 0; cc < 2; cc++) {
            int blk0 = (n2 << 2) + (cc << 1);
            vf[n2v][cc].u2[0] = *(const uint2*)(VB + vrowb + ((blk0 ^ swz) << 3) + (hi << 2));
            vf[n2v][cc].u2[1] =
                *(const uint2*)(VB + vrowb + (((blk0 + 1) ^ swz) << 3) + (hi << 2));
          }
        }
        // pack P into A-fragments (register-local; slot order matches V's b64 reads)
        union { uint32_t u[4]; bf16x8 v; } ap0, ap1;
#pragma unroll
        for (int g = 0; g < 4; g++) {
          ap0.u[g] = pk2(p[2 * g], p[2 * g + 1]);
          ap1.u[g] = pk2(p[8 + 2 * g], p[8 + 2 * g + 1]);
        }
        __builtin_amdgcn_s_setprio(1);
        acc0 = MFMA32(ap0.v, vf[0][0].v, acc0);
        acc1 = MFMA32(ap0.v, vf[1][0].v, acc1);
        acc0 = MFMA32(ap1.v, vf[0][1].v, acc0);
        acc1 = MFMA32(ap1.v, vf[1][1].v, acc1);
        __builtin_amdgcn_s_setprio(0);
      }
    }
    __syncthreads();
    cur ^= 1;
  }

  lsum += __shfl_xor(lsum, 32);
  float inv = 1.0f / lsum;
  int bb = bh >> 4, hh = bh & 15;
#pragma unroll
  for (int r = 0; r < 16; r++) {
    int qr = (r & 3) + ((r >> 2) << 3) + (hi << 2);
    float invq = __shfl(inv, qr);
    size_t base = ((size_t)(bb * Tt + qg + qr)) * Dd + (hh << 6) + l31;
    yb[base] = f2b(acc0[r] * invq);
    yb[base + 32] = f2b(acc1[r] * invq);
  }
}

extern "C" void kernel_launch(void* const* d_in, const int* in_sizes, int n_in,
                              void* d_out, int out_size, void* d_ws, size_t ws_size,
                              hipStream_t stream) {
  const float* x = (const float*)d_in[0];
  const float* Wk = (const float*)d_in[1];
  const float* bk = (const float*)d_in[2];
  const float* Wq = (const float*)d_in[3];
  const float* bq = (const float*)d_in[4];
  const float* Wv = (const float*)d_in[5];
  const float* bv = (const float*)d_in[6];
  const float* Wp = (const float*)d_in[7];
  const float* bp = (const float*)d_in[8];
  float* out = (float*)d_out;

  char* ws = (char*)d_ws;
  unsigned short* xb  = (unsigned short*)(ws);                       // 16MB
  unsigned short* WkT = (unsigned short*)(ws + (16ull << 20));       // 2MB each
  unsigned short* WqT = (unsigned short*)(ws + (18ull << 20));
  unsigned short* WvT = (unsigned short*)(ws + (20ull << 20));
  unsigned short* WpT = (unsigned short*)(ws + (22ull << 20));
  unsigned short* Qb  = (unsigned short*)(ws + (24ull << 20));       // 16MB
  unsigned short* Kb  = (unsigned short*)(ws + (40ull << 20));       // 16MB
  unsigned short* VTb = (unsigned short*)(ws + (56ull << 20));       // 16MB
  unsigned short* yb  = (unsigned short*)(ws + (72ull << 20));       // 16MB (ends 88MB)

  k_convert_x<<<4096, 256, 0, stream>>>(x, xb);
  k_transpose_w<<<dim3(1024, 4), 256, 0, stream>>>(Wk, Wq, Wv, Wp, WkT, WqT, WvT, WpT);
  k_gemm<<<dim3(64, 24), 256, 0, stream>>>(xb, WqT, WkT, WvT, bq, bk, bv,
                                           Qb, Kb, VTb, nullptr, 1);
  k_attn<<<1024, 256, 0, stream>>>(Qb, Kb, VTb, yb);
  k_gemm<<<dim3(64, 8), 256, 0, stream>>>(yb, WpT, nullptr, nullptr, bp, nullptr, nullptr,
                                          nullptr, nullptr, nullptr, out, 0);
}

// Round 9
// 216.725 us; speedup vs baseline: 2.2253x; 1.4366x over previous
//
#include <hip/hip_runtime.h>
#include <stdint.h>

#define Bb 4
#define Tt 2048
#define Dd 1024
#define Hh 16
#define HDd 64
#define Mm 8192   // Bb*Tt

typedef __attribute__((ext_vector_type(8))) short bf16x8;
typedef __attribute__((ext_vector_type(4))) float f32x4;
typedef __attribute__((ext_vector_type(16))) float f32x16;

#define MFMA(a, b, c) __builtin_amdgcn_mfma_f32_16x16x32_bf16(a, b, c, 0, 0, 0)
#define MFMA32(a, b, c) __builtin_amdgcn_mfma_f32_32x32x16_bf16(a, b, c, 0, 0, 0)

#define LOG2E 1.44269504088896340736f
#if __has_builtin(__builtin_amdgcn_exp2f)
#define EXP2(x) __builtin_amdgcn_exp2f(x)
#else
#define EXP2(x) __expf((x) * 0.69314718055994530942f)
#endif

union vfu { uint2 u2[2]; bf16x8 v; };
union apu { uint32_t u[4]; bf16x8 v; };

__device__ __forceinline__ unsigned short f2b(float f) {
  union { float f; uint32_t u; } v; v.f = f;
  return (unsigned short)((v.u + 0x7FFFu + ((v.u >> 16) & 1u)) >> 16);
}

// pack two f32 -> bf16x2 (compiler emits v_cvt_pk_bf16_f32)
__device__ __forceinline__ uint32_t pk2(float a, float b) {
  union { __bf16 h[2]; uint32_t u; } x;
  x.h[0] = (__bf16)a; x.h[1] = (__bf16)b;
  return x.u;
}

__device__ __forceinline__ void gload_lds16(const void* g, void* l) {
  __builtin_amdgcn_global_load_lds(
      (const __attribute__((address_space(1))) void*)g,
      (__attribute__((address_space(3))) void*)l, 16, 0, 0);
}

// ---------------- x f32 -> bf16 ----------------
__global__ __launch_bounds__(256) void k_convert_x(const float* __restrict__ x,
                                                   unsigned short* __restrict__ xb) {
  int i = (blockIdx.x * 256 + threadIdx.x) * 8;
  float4 a = *(const float4*)(x + i);
  float4 b = *(const float4*)(x + i + 4);
  uint4 o;
  o.x = f2b(a.x) | ((uint32_t)f2b(a.y) << 16);
  o.y = f2b(a.z) | ((uint32_t)f2b(a.w) << 16);
  o.z = f2b(b.x) | ((uint32_t)f2b(b.y) << 16);
  o.w = f2b(b.z) | ((uint32_t)f2b(b.w) << 16);
  *(uint4*)(xb + i) = o;
}

// ---------------- W [K][N] f32 -> Wt [N][K] bf16 ----------------
__global__ __launch_bounds__(256) void k_transpose_w(
    const float* __restrict__ Wk, const float* __restrict__ Wq,
    const float* __restrict__ Wv, const float* __restrict__ Wp,
    unsigned short* __restrict__ WkT, unsigned short* __restrict__ WqT,
    unsigned short* __restrict__ WvT, unsigned short* __restrict__ WpT) {
  const float* W; unsigned short* O;
  int wsel = blockIdx.y;
  W = wsel == 0 ? Wk : wsel == 1 ? Wq : wsel == 2 ? Wv : Wp;
  O = wsel == 0 ? WkT : wsel == 1 ? WqT : wsel == 2 ? WvT : WpT;
  __shared__ unsigned short tile[32][36];
  int kb = (blockIdx.x >> 5) << 5;
  int nb = (blockIdx.x & 31) << 5;
  int t = threadIdx.x;
  int r = t >> 3, c4 = (t & 7) << 2;
  float4 v = *(const float4*)(W + (size_t)(kb + r) * Dd + nb + c4);
  tile[r][c4 + 0] = f2b(v.x); tile[r][c4 + 1] = f2b(v.y);
  tile[r][c4 + 2] = f2b(v.z); tile[r][c4 + 3] = f2b(v.w);
  __syncthreads();
  uint2 o;
  o.x = tile[c4 + 0][r] | ((uint32_t)tile[c4 + 1][r] << 16);
  o.y = tile[c4 + 2][r] | ((uint32_t)tile[c4 + 3][r] << 16);
  *(uint2*)(O + (size_t)(nb + r) * Dd + kb + c4) = o;
}

// ---------------- GEMM: A[M][1024] bf16 @ Bt[N][1024]^T + bias ----------------
// qkv=1: Q,K -> [B,H,T,64] (K row-swizzled, Q pre-scaled by 0.125*log2e),
//        V -> [B,H,64,T] (t-swizzled)
// qkv=0: f32 out [M][1024]
__global__ __launch_bounds__(256) void k_gemm(
    const unsigned short* __restrict__ A,
    const unsigned short* __restrict__ Bt0, const unsigned short* __restrict__ Bt1,
    const unsigned short* __restrict__ Bt2,
    const float* __restrict__ bias0, const float* __restrict__ bias1,
    const float* __restrict__ bias2,
    unsigned short* __restrict__ Qb, unsigned short* __restrict__ Kb,
    unsigned short* __restrict__ VTb, float* __restrict__ Pout, int qkv) {
  __shared__ __align__(16) unsigned short Al[128 * 32];
  __shared__ __align__(16) unsigned short Bl[128 * 32];
  int tid = threadIdx.x;
  int lane = tid & 63, wid = tid >> 6;
  int wr = wid >> 1, wc = wid & 1;
  int lq = lane & 15, lh = lane >> 4;
  int mb = blockIdx.x * 128;
  int by = blockIdx.y;
  int widx, nb;
  const unsigned short* Bt; const float* bias;
  if (qkv) {
    widx = by >> 3; nb = (by & 7) << 7;
    Bt = widx == 0 ? Bt0 : (widx == 1 ? Bt1 : Bt2);
    bias = widx == 0 ? bias0 : (widx == 1 ? bias1 : bias2);
  } else {
    widx = 3; nb = by << 7; Bt = Bt0; bias = bias0;
  }

  int srow = (wid << 5) + (lane >> 2);
  int scol = (lane & 3) << 3;
  const unsigned short* Ag = A + (size_t)(mb + srow) * Dd + scol;
  const unsigned short* Bg = Bt + (size_t)(nb + srow) * Dd + scol;
  unsigned short* Alw = Al + (wid << 10);
  unsigned short* Blw = Bl + (wid << 10);

  f32x4 zero = {0.f, 0.f, 0.f, 0.f};
  f32x4 acc[4][4];
#pragma unroll
  for (int m = 0; m < 4; m++)
#pragma unroll
    for (int n = 0; n < 4; n++) acc[m][n] = zero;

  for (int kb = 0; kb < Dd; kb += 32) {
    __syncthreads();
    gload_lds16(Ag + kb, Alw);
    gload_lds16(Ag + kb + 16 * Dd, Alw + 16 * 32);
    gload_lds16(Bg + kb, Blw);
    gload_lds16(Bg + kb + 16 * Dd, Blw + 16 * 32);
    __syncthreads();
    bf16x8 af[4], bf[4];
#pragma unroll
    for (int m = 0; m < 4; m++)
      af[m] = *(const bf16x8*)(Al + (((wr << 6) + (m << 4) + lq) << 5) + (lh << 3));
#pragma unroll
    for (int n = 0; n < 4; n++)
      bf[n] = *(const bf16x8*)(Bl + (((wc << 6) + (n << 4) + lq) << 5) + (lh << 3));
#pragma unroll
    for (int m = 0; m < 4; m++)
#pragma unroll
      for (int n = 0; n < 4; n++) acc[m][n] = MFMA(af[m], bf[n], acc[m][n]);
  }

  int b_idx = mb >> 11;
#pragma unroll
  for (int n = 0; n < 4; n++) {
    int col = nb + (wc << 6) + (n << 4) + lq;
    float bb = bias[col];
    int hh = col >> 6, hd = col & 63;
#pragma unroll
    for (int m = 0; m < 4; m++) {
      int row0 = mb + (wr << 6) + (m << 4) + (lh << 2);
      int t0 = row0 & 2047;
      if (widx == 3) {
#pragma unroll
        for (int r = 0; r < 4; r++)
          Pout[(size_t)(row0 + r) * Dd + col] = acc[m][n][r] + bb;
      } else if (widx == 2) {
        float v0 = acc[m][n][0] + bb, v1 = acc[m][n][1] + bb;
        float v2 = acc[m][n][2] + bb, v3 = acc[m][n][3] + bb;
        uint2 pv;
        pv.x = f2b(v0) | ((uint32_t)f2b(v1) << 16);
        pv.y = f2b(v2) | ((uint32_t)f2b(v3) << 16);
        int t0s = t0 ^ ((hd & 7) << 3);  // V swizzle: t 16B-block ^= hd&7
        *(uint2*)(VTb + ((size_t)(b_idx * 16 + hh) * 64 + hd) * Tt + t0s) = pv;
      } else {
        unsigned short* O = (widx == 0) ? Qb : Kb;
        float sc = (widx == 0) ? (0.125f * LOG2E) : 1.0f;  // fold scale*log2e into Q
#pragma unroll
        for (int r = 0; r < 4; r++) {
          float v = (acc[m][n][r] + bb) * sc;
          int trow = t0 + r;
          int hds = (widx == 0) ? hd : (hd ^ ((trow & 7) << 3));  // K swizzle
          O[((size_t)(b_idx * 16 + hh) * Tt + trow) * 64 + hds] = f2b(v);
        }
      }
    }
  }
}

// ---------------- flash attention (causal), Q pre-scaled by 0.125*log2e ----------
// r8 structure with the spill fixed: __launch_bounds__(256, 4) -> VGPR cap 128
// (r8's (256,5) capped at ~102 and spilled acc to scratch: VGPR 48, +55MB
// scratch writes, 205us). Everything else identical to r8.
__global__ __launch_bounds__(256, 4) void k_attn(
    const unsigned short* __restrict__ Qb, const unsigned short* __restrict__ Kb,
    const unsigned short* __restrict__ VTb, unsigned short* __restrict__ yb) {
  __shared__ __align__(16) unsigned short KL[2][4096];
  __shared__ __align__(16) unsigned short VL[2][4096];
  int raw = blockIdx.x;
  int blk = ((raw & 7) << 7) | (raw >> 3);   // XCD chunk (1024%8==0, bijective)
  int bh = blk >> 4;
  int qt = 15 - (blk & 15);                  // heavy q-tiles first
  int tid = threadIdx.x, lane = tid & 63, w = tid >> 6;
  int l31 = lane & 31, hi = lane >> 5;
  const unsigned short* __restrict__ Qh = Qb + (size_t)bh * Tt * 64;
  const unsigned short* __restrict__ Kh = Kb + (size_t)bh * Tt * 64;
  const unsigned short* __restrict__ Vh = VTb + (size_t)bh * 64 * Tt;
  int qg = (qt << 7) + (w << 5);             // wave's 32 q rows

  // Q B-fragments: lane holds Q[qg+l31][16c + 8hi + j]
  bf16x8 qf[4];
#pragma unroll
  for (int c = 0; c < 4; c++)
    qf[c] = *(const bf16x8*)(Qh + (size_t)(qg + l31) * 64 + (c << 4) + (hi << 3));

  f32x16 acc0, acc1;
#pragma unroll
  for (int i = 0; i < 16; i++) { acc0[i] = 0.f; acc1[i] = 0.f; }
  float lsum = 0.f;

  int jmax = (qt << 1) + 1;    // 64-row kv tiles: 0..jmax covers the q-tile diag
  int srow = lane >> 3, scol = (lane & 7) << 3;
  int rowb = w << 4;           // wave stages 16 rows of K and of V per tile
  int swz = l31 & 7;

  // prologue: stage tile 0 into buf 0
  gload_lds16(Kh + (size_t)(rowb + srow) * 64 + scol, &KL[0][rowb << 6]);
  gload_lds16(Kh + (size_t)(rowb + 8 + srow) * 64 + scol, &KL[0][(rowb + 8) << 6]);
  gload_lds16(Vh + (size_t)(rowb + srow) * Tt + scol, &VL[0][rowb << 6]);
  gload_lds16(Vh + (size_t)(rowb + 8 + srow) * Tt + scol, &VL[0][(rowb + 8) << 6]);
  __syncthreads();

  int cur = 0;
  for (int jt = 0; jt <= jmax; ++jt) {
    if (jt < jmax) {  // stage next tile into the other buffer (hides under compute)
      int kv1 = (jt + 1) << 6;
      gload_lds16(Kh + (size_t)(kv1 + rowb + srow) * 64 + scol, &KL[cur ^ 1][rowb << 6]);
      gload_lds16(Kh + (size_t)(kv1 + rowb + 8 + srow) * 64 + scol,
                  &KL[cur ^ 1][(rowb + 8) << 6]);
      gload_lds16(Vh + (size_t)(rowb + srow) * Tt + kv1 + scol, &VL[cur ^ 1][rowb << 6]);
      gload_lds16(Vh + (size_t)(rowb + 8 + srow) * Tt + kv1 + scol,
                  &VL[cur ^ 1][(rowb + 8) << 6]);
    }
    int kv0 = jt << 6;
    int d = qg - kv0;   // wave-uniform
    if (d >= 0) {
      const unsigned short* KB = &KL[cur][0];
      const unsigned short* VB = &VL[cur][0];
      bool diag = (d < 64);
      int rel = d + l31;
#pragma unroll
      for (int n2 = 0; n2 < 2; n2++) {
        // K fragments for this kv-half
        bf16x8 kf[4];
        int krowb = ((n2 << 5) + l31) << 6;
#pragma unroll
        for (int c = 0; c < 4; c++)
          kf[c] = *(const bf16x8*)(KB + krowb + ((((c << 1) + hi) ^ swz) << 3));
        f32x16 s;
#pragma unroll
        for (int i = 0; i < 16; i++) s[i] = 0.f;
        __builtin_amdgcn_s_setprio(1);
#pragma unroll
        for (int c = 0; c < 4; c++) s = MFMA32(kf[c], qf[c], s);
        __builtin_amdgcn_s_setprio(0);
        float p[16];
        if (diag) {
#pragma unroll
          for (int r = 0; r < 16; r++) {
            int krow = (n2 << 5) + (r & 3) + ((r >> 2) << 3) + (hi << 2);
            p[r] = EXP2(krow > rel ? -1e30f : s[r]);
          }
        } else {
#pragma unroll
          for (int r = 0; r < 16; r++) p[r] = EXP2(s[r]);
        }
        lsum += (((p[0] + p[1]) + (p[2] + p[3])) + ((p[4] + p[5]) + (p[6] + p[7])))
              + (((p[8] + p[9]) + (p[10] + p[11])) + ((p[12] + p[13]) + (p[14] + p[15])));
        // V fragments: element (hi,j) = V[kv0 + 32n2 + 16cc + 8(j>>2)+4hi+(j&3)][hd]
        union { uint2 u2[2]; bf16x8 v; } vf[2][2];
#pragma unroll
        for (int n2v = 0; n2v < 2; n2v++) {
          int vrowb = ((n2v << 5) + l31) << 6;
#pragma unroll
          for (int cc = 0; cc < 2; cc++) {
            int blk0 = (n2 << 2) + (cc << 1);
            vf[n2v][cc].u2[0] = *(const uint2*)(VB + vrowb + ((blk0 ^ swz) << 3) + (hi << 2));
            vf[n2v][cc].u2[1] =
                *(const uint2*)(VB + vrowb + (((blk0 + 1) ^ swz) << 3) + (hi << 2));
          }
        }
        // pack P into A-fragments (register-local; slot order matches V's b64 reads)
        union { uint32_t u[4]; bf16x8 v; } ap0, ap1;
#pragma unroll
        for (int g = 0; g < 4; g++) {
          ap0.u[g] = pk2(p[2 * g], p[2 * g + 1]);
          ap1.u[g] = pk2(p[8 + 2 * g], p[8 + 2 * g + 1]);
        }
        __builtin_amdgcn_s_setprio(1);
        acc0 = MFMA32(ap0.v, vf[0][0].v, acc0);
        acc1 = MFMA32(ap0.v, vf[1][0].v, acc1);
        acc0 = MFMA32(ap1.v, vf[0][1].v, acc0);
        acc1 = MFMA32(ap1.v, vf[1][1].v, acc1);
        __builtin_amdgcn_s_setprio(0);
      }
    }
    __syncthreads();
    cur ^= 1;
  }

  lsum += __shfl_xor(lsum, 32);
  float inv = 1.0f / lsum;
  int bb = bh >> 4, hh = bh & 15;
#pragma unroll
  for (int r = 0; r < 16; r++) {
    int qr = (r & 3) + ((r >> 2) << 3) + (hi << 2);
    float invq = __shfl(inv, qr);
    size_t base = ((size_t)(bb * Tt + qg + qr)) * Dd + (hh << 6) + l31;
    yb[base] = f2b(acc0[r] * invq);
    yb[base + 32] = f2b(acc1[r] * invq);
  }
}

extern "C" void kernel_launch(void* const* d_in, const int* in_sizes, int n_in,
                              void* d_out, int out_size, void* d_ws, size_t ws_size,
                              hipStream_t stream) {
  const float* x = (const float*)d_in[0];
  const float* Wk = (const float*)d_in[1];
  const float* bk = (const float*)d_in[2];
  const float* Wq = (const float*)d_in[3];
  const float* bq = (const float*)d_in[4];
  const float* Wv = (const float*)d_in[5];
  const float* bv = (const float*)d_in[6];
  const float* Wp = (const float*)d_in[7];
  const float* bp = (const float*)d_in[8];
  float* out = (float*)d_out;

  char* ws = (char*)d_ws;
  unsigned short* xb  = (unsigned short*)(ws);                       // 16MB
  unsigned short* WkT = (unsigned short*)(ws + (16ull << 20));       // 2MB each
  unsigned short* WqT = (unsigned short*)(ws + (18ull << 20));
  unsigned short* WvT = (unsigned short*)(ws + (20ull << 20));
  unsigned short* WpT = (unsigned short*)(ws + (22ull << 20));
  unsigned short* Qb  = (unsigned short*)(ws + (24ull << 20));       // 16MB
  unsigned short* Kb  = (unsigned short*)(ws + (40ull << 20));       // 16MB
  unsigned short* VTb = (unsigned short*)(ws + (56ull << 20));       // 16MB
  unsigned short* yb  = (unsigned short*)(ws + (72ull << 20));       // 16MB (ends 88MB)

  k_convert_x<<<4096, 256, 0, stream>>>(x, xb);
  k_transpose_w<<<dim3(1024, 4), 256, 0, stream>>>(Wk, Wq, Wv, Wp, WkT, WqT, WvT, WpT);
  k_gemm<<<dim3(64, 24), 256, 0, stream>>>(xb, WqT, WkT, WvT, bq, bk, bv,
                                           Qb, Kb, VTb, nullptr, 1);
  k_attn<<<1024, 256, 0, stream>>>(Qb, Kb, VTb, yb);
  k_gemm<<<dim3(64, 8), 256, 0, stream>>>(yb, WpT, nullptr, nullptr, bp, nullptr, nullptr,
                                          nullptr, nullptr, nullptr, out, 0);
}

// Round 10
// 209.512 us; speedup vs baseline: 2.3019x; 1.0344x over previous
//
#include <hip/hip_runtime.h>
#include <stdint.h>

#define Bb 4
#define Tt 2048
#define Dd 1024
#define Hh 16
#define HDd 64
#define Mm 8192   // Bb*Tt

typedef __attribute__((ext_vector_type(8))) short bf16x8;
typedef __attribute__((ext_vector_type(4))) float f32x4;
typedef __attribute__((ext_vector_type(16))) float f32x16;

#define MFMA(a, b, c) __builtin_amdgcn_mfma_f32_16x16x32_bf16(a, b, c, 0, 0, 0)
#define MFMA32(a, b, c) __builtin_amdgcn_mfma_f32_32x32x16_bf16(a, b, c, 0, 0, 0)

#define LOG2E 1.44269504088896340736f
#if __has_builtin(__builtin_amdgcn_exp2f)
#define EXP2(x) __builtin_amdgcn_exp2f(x)
#else
#define EXP2(x) __expf((x) * 0.69314718055994530942f)
#endif

union vfu { uint2 u2[2]; bf16x8 v; };
union apu { uint32_t u[4]; bf16x8 v; };

__device__ __forceinline__ unsigned short f2b(float f) {
  union { float f; uint32_t u; } v; v.f = f;
  return (unsigned short)((v.u + 0x7FFFu + ((v.u >> 16) & 1u)) >> 16);
}

// pack two f32 -> bf16x2 (compiler emits v_cvt_pk_bf16_f32)
__device__ __forceinline__ uint32_t pk2(float a, float b) {
  union { __bf16 h[2]; uint32_t u; } x;
  x.h[0] = (__bf16)a; x.h[1] = (__bf16)b;
  return x.u;
}

__device__ __forceinline__ void gload_lds16(const void* g, void* l) {
  __builtin_amdgcn_global_load_lds(
      (const __attribute__((address_space(1))) void*)g,
      (__attribute__((address_space(3))) void*)l, 16, 0, 0);
}

// ---------------- x f32 -> bf16 ----------------
__global__ __launch_bounds__(256) void k_convert_x(const float* __restrict__ x,
                                                   unsigned short* __restrict__ xb) {
  int i = (blockIdx.x * 256 + threadIdx.x) * 8;
  float4 a = *(const float4*)(x + i);
  float4 b = *(const float4*)(x + i + 4);
  uint4 o;
  o.x = f2b(a.x) | ((uint32_t)f2b(a.y) << 16);
  o.y = f2b(a.z) | ((uint32_t)f2b(a.w) << 16);
  o.z = f2b(b.x) | ((uint32_t)f2b(b.y) << 16);
  o.w = f2b(b.z) | ((uint32_t)f2b(b.w) << 16);
  *(uint4*)(xb + i) = o;
}

// ---------------- W [K][N] f32 -> Wt [N][K] bf16 ----------------
__global__ __launch_bounds__(256) void k_transpose_w(
    const float* __restrict__ Wk, const float* __restrict__ Wq,
    const float* __restrict__ Wv, const float* __restrict__ Wp,
    unsigned short* __restrict__ WkT, unsigned short* __restrict__ WqT,
    unsigned short* __restrict__ WvT, unsigned short* __restrict__ WpT) {
  const float* W; unsigned short* O;
  int wsel = blockIdx.y;
  W = wsel == 0 ? Wk : wsel == 1 ? Wq : wsel == 2 ? Wv : Wp;
  O = wsel == 0 ? WkT : wsel == 1 ? WqT : wsel == 2 ? WvT : WpT;
  __shared__ unsigned short tile[32][36];
  int kb = (blockIdx.x >> 5) << 5;
  int nb = (blockIdx.x & 31) << 5;
  int t = threadIdx.x;
  int r = t >> 3, c4 = (t & 7) << 2;
  float4 v = *(const float4*)(W + (size_t)(kb + r) * Dd + nb + c4);
  tile[r][c4 + 0] = f2b(v.x); tile[r][c4 + 1] = f2b(v.y);
  tile[r][c4 + 2] = f2b(v.z); tile[r][c4 + 3] = f2b(v.w);
  __syncthreads();
  uint2 o;
  o.x = tile[c4 + 0][r] | ((uint32_t)tile[c4 + 1][r] << 16);
  o.y = tile[c4 + 2][r] | ((uint32_t)tile[c4 + 3][r] << 16);
  *(uint2*)(O + (size_t)(nb + r) * Dd + kb + c4) = o;
}

// ---------------- GEMM: A[M][1024] bf16 @ Bt[N][1024]^T + bias ----------------
// qkv=1: Q,K -> [B,H,T,64] (K row-swizzled, Q pre-scaled by 0.125*log2e),
//        V -> [B,H,64,T] (t-swizzled)
// qkv=0: f32 out [M][1024]
__global__ __launch_bounds__(256) void k_gemm(
    const unsigned short* __restrict__ A,
    const unsigned short* __restrict__ Bt0, const unsigned short* __restrict__ Bt1,
    const unsigned short* __restrict__ Bt2,
    const float* __restrict__ bias0, const float* __restrict__ bias1,
    const float* __restrict__ bias2,
    unsigned short* __restrict__ Qb, unsigned short* __restrict__ Kb,
    unsigned short* __restrict__ VTb, float* __restrict__ Pout, int qkv) {
  __shared__ __align__(16) unsigned short Al[128 * 32];
  __shared__ __align__(16) unsigned short Bl[128 * 32];
  int tid = threadIdx.x;
  int lane = tid & 63, wid = tid >> 6;
  int wr = wid >> 1, wc = wid & 1;
  int lq = lane & 15, lh = lane >> 4;
  int mb = blockIdx.x * 128;
  int by = blockIdx.y;
  int widx, nb;
  const unsigned short* Bt; const float* bias;
  if (qkv) {
    widx = by >> 3; nb = (by & 7) << 7;
    Bt = widx == 0 ? Bt0 : (widx == 1 ? Bt1 : Bt2);
    bias = widx == 0 ? bias0 : (widx == 1 ? bias1 : bias2);
  } else {
    widx = 3; nb = by << 7; Bt = Bt0; bias = bias0;
  }

  int srow = (wid << 5) + (lane >> 2);
  int scol = (lane & 3) << 3;
  const unsigned short* Ag = A + (size_t)(mb + srow) * Dd + scol;
  const unsigned short* Bg = Bt + (size_t)(nb + srow) * Dd + scol;
  unsigned short* Alw = Al + (wid << 10);
  unsigned short* Blw = Bl + (wid << 10);

  f32x4 zero = {0.f, 0.f, 0.f, 0.f};
  f32x4 acc[4][4];
#pragma unroll
  for (int m = 0; m < 4; m++)
#pragma unroll
    for (int n = 0; n < 4; n++) acc[m][n] = zero;

  for (int kb = 0; kb < Dd; kb += 32) {
    __syncthreads();
    gload_lds16(Ag + kb, Alw);
    gload_lds16(Ag + kb + 16 * Dd, Alw + 16 * 32);
    gload_lds16(Bg + kb, Blw);
    gload_lds16(Bg + kb + 16 * Dd, Blw + 16 * 32);
    __syncthreads();
    bf16x8 af[4], bf[4];
#pragma unroll
    for (int m = 0; m < 4; m++)
      af[m] = *(const bf16x8*)(Al + (((wr << 6) + (m << 4) + lq) << 5) + (lh << 3));
#pragma unroll
    for (int n = 0; n < 4; n++)
      bf[n] = *(const bf16x8*)(Bl + (((wc << 6) + (n << 4) + lq) << 5) + (lh << 3));
#pragma unroll
    for (int m = 0; m < 4; m++)
#pragma unroll
      for (int n = 0; n < 4; n++) acc[m][n] = MFMA(af[m], bf[n], acc[m][n]);
  }

  int b_idx = mb >> 11;
#pragma unroll
  for (int n = 0; n < 4; n++) {
    int col = nb + (wc << 6) + (n << 4) + lq;
    float bb = bias[col];
    int hh = col >> 6, hd = col & 63;
#pragma unroll
    for (int m = 0; m < 4; m++) {
      int row0 = mb + (wr << 6) + (m << 4) + (lh << 2);
      int t0 = row0 & 2047;
      if (widx == 3) {
#pragma unroll
        for (int r = 0; r < 4; r++)
          Pout[(size_t)(row0 + r) * Dd + col] = acc[m][n][r] + bb;
      } else if (widx == 2) {
        float v0 = acc[m][n][0] + bb, v1 = acc[m][n][1] + bb;
        float v2 = acc[m][n][2] + bb, v3 = acc[m][n][3] + bb;
        uint2 pv;
        pv.x = f2b(v0) | ((uint32_t)f2b(v1) << 16);
        pv.y = f2b(v2) | ((uint32_t)f2b(v3) << 16);
        int t0s = t0 ^ ((hd & 7) << 3);  // V swizzle: t 16B-block ^= hd&7
        *(uint2*)(VTb + ((size_t)(b_idx * 16 + hh) * 64 + hd) * Tt + t0s) = pv;
      } else {
        unsigned short* O = (widx == 0) ? Qb : Kb;
        float sc = (widx == 0) ? (0.125f * LOG2E) : 1.0f;  // fold scale*log2e into Q
#pragma unroll
        for (int r = 0; r < 4; r++) {
          float v = (acc[m][n][r] + bb) * sc;
          int trow = t0 + r;
          int hds = (widx == 0) ? hd : (hd ^ ((trow & 7) << 3));  // K swizzle
          O[((size_t)(b_idx * 16 + hh) * Tt + trow) * 64 + hds] = f2b(v);
        }
      }
    }
  }
}

// ---------------- flash attention (causal), Q pre-scaled by 0.125*log2e ----------
// r9 structure + counted-vmcnt pipeline (T4): 3 staging buffers, raw s_barrier,
// s_waitcnt vmcnt(4) instead of the __syncthreads vmcnt(0) drain. stage(t+2) is
// issued AFTER the barrier (all waves past compute(t-1), so buf[(t+2)%3] is free)
// and its latency hides under two tiles of compute.
__global__ __launch_bounds__(256, 4) void k_attn(
    const unsigned short* __restrict__ Qb, const unsigned short* __restrict__ Kb,
    const unsigned short* __restrict__ VTb, unsigned short* __restrict__ yb) {
  __shared__ __align__(16) unsigned short KL[3][4096];
  __shared__ __align__(16) unsigned short VL[3][4096];
  int raw = blockIdx.x;
  int blk = ((raw & 7) << 7) | (raw >> 3);   // XCD chunk (1024%8==0, bijective)
  int bh = blk >> 4;
  int qt = 15 - (blk & 15);                  // heavy q-tiles first
  int tid = threadIdx.x, lane = tid & 63, w = tid >> 6;
  int l31 = lane & 31, hi = lane >> 5;
  const unsigned short* __restrict__ Qh = Qb + (size_t)bh * Tt * 64;
  const unsigned short* __restrict__ Kh = Kb + (size_t)bh * Tt * 64;
  const unsigned short* __restrict__ Vh = VTb + (size_t)bh * 64 * Tt;
  int qg = (qt << 7) + (w << 5);             // wave's 32 q rows

  // Q B-fragments: lane holds Q[qg+l31][16c + 8hi + j]
  bf16x8 qf[4];
#pragma unroll
  for (int c = 0; c < 4; c++)
    qf[c] = *(const bf16x8*)(Qh + (size_t)(qg + l31) * 64 + (c << 4) + (hi << 3));

  f32x16 acc0, acc1;
#pragma unroll
  for (int i = 0; i < 16; i++) { acc0[i] = 0.f; acc1[i] = 0.f; }
  float lsum = 0.f;

  int jmax = (qt << 1) + 1;    // 64-row kv tiles: 0..jmax covers the q-tile diag
  int srow = lane >> 3, scol = (lane & 7) << 3;
  int rowb = w << 4;           // wave stages 16 rows of K and of V per tile
  int swz = l31 & 7;

#define STAGE(kvt_, bi_) do {                                                       \
    int kv_ = (kvt_) << 6;                                                          \
    gload_lds16(Kh + (size_t)(kv_ + rowb + srow) * 64 + scol, &KL[bi_][rowb << 6]); \
    gload_lds16(Kh + (size_t)(kv_ + rowb + 8 + srow) * 64 + scol,                   \
                &KL[bi_][(rowb + 8) << 6]);                                         \
    gload_lds16(Vh + (size_t)(rowb + srow) * Tt + kv_ + scol, &VL[bi_][rowb << 6]); \
    gload_lds16(Vh + (size_t)(rowb + 8 + srow) * Tt + kv_ + scol,                   \
                &VL[bi_][(rowb + 8) << 6]);                                         \
  } while (0)

  // prologue: 2 tiles in flight (4 loads each per wave)
  STAGE(0, 0);
  STAGE(1, 1);

  int cur = 0, nx2 = 2;
  for (int jt = 0; jt <= jmax; ++jt) {
    // wait for THIS wave's tile-jt loads (4 newer loads may stay in flight),
    // then barrier: all waves' tile-jt staged AND all waves done with compute(jt-1)
    if (jt < jmax) {
      asm volatile("s_waitcnt vmcnt(4)" ::: "memory");
    } else {
      asm volatile("s_waitcnt vmcnt(0)" ::: "memory");
    }
    __builtin_amdgcn_s_barrier();
    if (jt + 2 <= jmax) STAGE(jt + 2, nx2);   // buf[(jt+2)%3] free: readers were compute(jt-1)

    int kv0 = jt << 6;
    int d = qg - kv0;   // wave-uniform
    if (d >= 0) {
      const unsigned short* KB = &KL[cur][0];
      const unsigned short* VB = &VL[cur][0];
      bool diag = (d < 64);
      int rel = d + l31;
#pragma unroll
      for (int n2 = 0; n2 < 2; n2++) {
        // K fragments for this kv-half
        bf16x8 kf[4];
        int krowb = ((n2 << 5) + l31) << 6;
#pragma unroll
        for (int c = 0; c < 4; c++)
          kf[c] = *(const bf16x8*)(KB + krowb + ((((c << 1) + hi) ^ swz) << 3));
        f32x16 s;
#pragma unroll
        for (int i = 0; i < 16; i++) s[i] = 0.f;
        __builtin_amdgcn_s_setprio(1);
#pragma unroll
        for (int c = 0; c < 4; c++) s = MFMA32(kf[c], qf[c], s);
        __builtin_amdgcn_s_setprio(0);
        float p[16];
        if (diag) {
#pragma unroll
          for (int r = 0; r < 16; r++) {
            int krow = (n2 << 5) + (r & 3) + ((r >> 2) << 3) + (hi << 2);
            p[r] = EXP2(krow > rel ? -1e30f : s[r]);
          }
        } else {
#pragma unroll
          for (int r = 0; r < 16; r++) p[r] = EXP2(s[r]);
        }
        lsum += (((p[0] + p[1]) + (p[2] + p[3])) + ((p[4] + p[5]) + (p[6] + p[7])))
              + (((p[8] + p[9]) + (p[10] + p[11])) + ((p[12] + p[13]) + (p[14] + p[15])));
        // V fragments: element (hi,j) = V[kv0 + 32n2 + 16cc + 8(j>>2)+4hi+(j&3)][hd]
        union { uint2 u2[2]; bf16x8 v; } vf[2][2];
#pragma unroll
        for (int n2v = 0; n2v < 2; n2v++) {
          int vrowb = ((n2v << 5) + l31) << 6;
#pragma unroll
          for (int cc = 0; cc < 2; cc++) {
            int blk0 = (n2 << 2) + (cc << 1);
            vf[n2v][cc].u2[0] = *(const uint2*)(VB + vrowb + ((blk0 ^ swz) << 3) + (hi << 2));
            vf[n2v][cc].u2[1] =
                *(const uint2*)(VB + vrowb + (((blk0 + 1) ^ swz) << 3) + (hi << 2));
          }
        }
        // pack P into A-fragments (register-local; slot order matches V's b64 reads)
        union { uint32_t u[4]; bf16x8 v; } ap0, ap1;
#pragma unroll
        for (int g = 0; g < 4; g++) {
          ap0.u[g] = pk2(p[2 * g], p[2 * g + 1]);
          ap1.u[g] = pk2(p[8 + 2 * g], p[8 + 2 * g + 1]);
        }
        __builtin_amdgcn_s_setprio(1);
        acc0 = MFMA32(ap0.v, vf[0][0].v, acc0);
        acc1 = MFMA32(ap0.v, vf[1][0].v, acc1);
        acc0 = MFMA32(ap1.v, vf[0][1].v, acc0);
        acc1 = MFMA32(ap1.v, vf[1][1].v, acc1);
        __builtin_amdgcn_s_setprio(0);
      }
    }
    cur = (cur == 2) ? 0 : cur + 1;
    nx2 = (nx2 == 2) ? 0 : nx2 + 1;
  }
#undef STAGE

  lsum += __shfl_xor(lsum, 32);
  float inv = 1.0f / lsum;
  int bb = bh >> 4, hh = bh & 15;
#pragma unroll
  for (int r = 0; r < 16; r++) {
    int qr = (r & 3) + ((r >> 2) << 3) + (hi << 2);
    float invq = __shfl(inv, qr);
    size_t base = ((size_t)(bb * Tt + qg + qr)) * Dd + (hh << 6) + l31;
    yb[base] = f2b(acc0[r] * invq);
    yb[base + 32] = f2b(acc1[r] * invq);
  }
}

extern "C" void kernel_launch(void* const* d_in, const int* in_sizes, int n_in,
                              void* d_out, int out_size, void* d_ws, size_t ws_size,
                              hipStream_t stream) {
  const float* x = (const float*)d_in[0];
  const float* Wk = (const float*)d_in[1];
  const float* bk = (const float*)d_in[2];
  const float* Wq = (const float*)d_in[3];
  const float* bq = (const float*)d_in[4];
  const float* Wv = (const float*)d_in[5];
  const float* bv = (const float*)d_in[6];
  const float* Wp = (const float*)d_in[7];
  const float* bp = (const float*)d_in[8];
  float* out = (float*)d_out;

  char* ws = (char*)d_ws;
  unsigned short* xb  = (unsigned short*)(ws);                       // 16MB
  unsigned short* WkT = (unsigned short*)(ws + (16ull << 20));       // 2MB each
  unsigned short* WqT = (unsigned short*)(ws + (18ull << 20));
  unsigned short* WvT = (unsigned short*)(ws + (20ull << 20));
  unsigned short* WpT = (unsigned short*)(ws + (22ull << 20));
  unsigned short* Qb  = (unsigned short*)(ws + (24ull << 20));       // 16MB
  unsigned short* Kb  = (unsigned short*)(ws + (40ull << 20));       // 16MB
  unsigned short* VTb = (unsigned short*)(ws + (56ull << 20));       // 16MB
  unsigned short* yb  = (unsigned short*)(ws + (72ull << 20));       // 16MB (ends 88MB)

  k_convert_x<<<4096, 256, 0, stream>>>(x, xb);
  k_transpose_w<<<dim3(1024, 4), 256, 0, stream>>>(Wk, Wq, Wv, Wp, WkT, WqT, WvT, WpT);
  k_gemm<<<dim3(64, 24), 256, 0, stream>>>(xb, WqT, WkT, WvT, bq, bk, bv,
                                           Qb, Kb, VTb, nullptr, 1);
  k_attn<<<1024, 256, 0, stream>>>(Qb, Kb, VTb, yb);
  k_gemm<<<dim3(64, 8), 256, 0, stream>>>(yb, WpT, nullptr, nullptr, bp, nullptr, nullptr,
                                          nullptr, nullptr, nullptr, out, 0);
}

// Round 11
// 195.160 us; speedup vs baseline: 2.4712x; 1.0735x over previous
//
#include <hip/hip_runtime.h>
#include <stdint.h>

#define Bb 4
#define Tt 2048
#define Dd 1024
#define Hh 16
#define HDd 64
#define Mm 8192   // Bb*Tt

typedef __attribute__((ext_vector_type(8))) short bf16x8;
typedef __attribute__((ext_vector_type(4))) float f32x4;
typedef __attribute__((ext_vector_type(16))) float f32x16;

#define MFMA(a, b, c) __builtin_amdgcn_mfma_f32_16x16x32_bf16(a, b, c, 0, 0, 0)
#define MFMA32(a, b, c) __builtin_amdgcn_mfma_f32_32x32x16_bf16(a, b, c, 0, 0, 0)

#define LOG2E 1.44269504088896340736f
#if __has_builtin(__builtin_amdgcn_exp2f)
#define EXP2(x) __builtin_amdgcn_exp2f(x)
#else
#define EXP2(x) __expf((x) * 0.69314718055994530942f)
#endif

#define N_ITEMS 1024

__device__ int g_ctr;

union vfu { uint2 u2[2]; bf16x8 v; };
union apu { uint32_t u[4]; bf16x8 v; };

__device__ __forceinline__ unsigned short f2b(float f) {
  union { float f; uint32_t u; } v; v.f = f;
  return (unsigned short)((v.u + 0x7FFFu + ((v.u >> 16) & 1u)) >> 16);
}

// pack two f32 -> bf16x2 (compiler emits v_cvt_pk_bf16_f32)
__device__ __forceinline__ uint32_t pk2(float a, float b) {
  union { __bf16 h[2]; uint32_t u; } x;
  x.h[0] = (__bf16)a; x.h[1] = (__bf16)b;
  return x.u;
}

__device__ __forceinline__ void gload_lds16(const void* g, void* l) {
  __builtin_amdgcn_global_load_lds(
      (const __attribute__((address_space(1))) void*)g,
      (__attribute__((address_space(3))) void*)l, 16, 0, 0);
}

// ---------------- x f32 -> bf16 (also resets the attn work-queue) ----------------
__global__ __launch_bounds__(256) void k_convert_x(const float* __restrict__ x,
                                                   unsigned short* __restrict__ xb) {
  if ((blockIdx.x | threadIdx.x) == 0) atomicExch(&g_ctr, 0);
  int i = (blockIdx.x * 256 + threadIdx.x) * 8;
  float4 a = *(const float4*)(x + i);
  float4 b = *(const float4*)(x + i + 4);
  uint4 o;
  o.x = f2b(a.x) | ((uint32_t)f2b(a.y) << 16);
  o.y = f2b(a.z) | ((uint32_t)f2b(a.w) << 16);
  o.z = f2b(b.x) | ((uint32_t)f2b(b.y) << 16);
  o.w = f2b(b.z) | ((uint32_t)f2b(b.w) << 16);
  *(uint4*)(xb + i) = o;
}

// ---------------- W [K][N] f32 -> Wt [N][K] bf16 ----------------
__global__ __launch_bounds__(256) void k_transpose_w(
    const float* __restrict__ Wk, const float* __restrict__ Wq,
    const float* __restrict__ Wv, const float* __restrict__ Wp,
    unsigned short* __restrict__ WkT, unsigned short* __restrict__ WqT,
    unsigned short* __restrict__ WvT, unsigned short* __restrict__ WpT) {
  const float* W; unsigned short* O;
  int wsel = blockIdx.y;
  W = wsel == 0 ? Wk : wsel == 1 ? Wq : wsel == 2 ? Wv : Wp;
  O = wsel == 0 ? WkT : wsel == 1 ? WqT : wsel == 2 ? WvT : WpT;
  __shared__ unsigned short tile[32][36];
  int kb = (blockIdx.x >> 5) << 5;
  int nb = (blockIdx.x & 31) << 5;
  int t = threadIdx.x;
  int r = t >> 3, c4 = (t & 7) << 2;
  float4 v = *(const float4*)(W + (size_t)(kb + r) * Dd + nb + c4);
  tile[r][c4 + 0] = f2b(v.x); tile[r][c4 + 1] = f2b(v.y);
  tile[r][c4 + 2] = f2b(v.z); tile[r][c4 + 3] = f2b(v.w);
  __syncthreads();
  uint2 o;
  o.x = tile[c4 + 0][r] | ((uint32_t)tile[c4 + 1][r] << 16);
  o.y = tile[c4 + 2][r] | ((uint32_t)tile[c4 + 3][r] << 16);
  *(uint2*)(O + (size_t)(nb + r) * Dd + kb + c4) = o;
}

// ---------------- GEMM: A[M][1024] bf16 @ Bt[N][1024]^T + bias ----------------
// qkv=1: Q,K -> [B,H,T,64] (K row-swizzled, Q pre-scaled by 0.125*log2e),
//        V -> [B,H,64,T] (t-swizzled)
// qkv=0: f32 out [M][1024]
__global__ __launch_bounds__(256) void k_gemm(
    const unsigned short* __restrict__ A,
    const unsigned short* __restrict__ Bt0, const unsigned short* __restrict__ Bt1,
    const unsigned short* __restrict__ Bt2,
    const float* __restrict__ bias0, const float* __restrict__ bias1,
    const float* __restrict__ bias2,
    unsigned short* __restrict__ Qb, unsigned short* __restrict__ Kb,
    unsigned short* __restrict__ VTb, float* __restrict__ Pout, int qkv) {
  __shared__ __align__(16) unsigned short Al[128 * 32];
  __shared__ __align__(16) unsigned short Bl[128 * 32];
  int tid = threadIdx.x;
  int lane = tid & 63, wid = tid >> 6;
  int wr = wid >> 1, wc = wid & 1;
  int lq = lane & 15, lh = lane >> 4;
  int mb = blockIdx.x * 128;
  int by = blockIdx.y;
  int widx, nb;
  const unsigned short* Bt; const float* bias;
  if (qkv) {
    widx = by >> 3; nb = (by & 7) << 7;
    Bt = widx == 0 ? Bt0 : (widx == 1 ? Bt1 : Bt2);
    bias = widx == 0 ? bias0 : (widx == 1 ? bias1 : bias2);
  } else {
    widx = 3; nb = by << 7; Bt = Bt0; bias = bias0;
  }

  int srow = (wid << 5) + (lane >> 2);
  int scol = (lane & 3) << 3;
  const unsigned short* Ag = A + (size_t)(mb + srow) * Dd + scol;
  const unsigned short* Bg = Bt + (size_t)(nb + srow) * Dd + scol;
  unsigned short* Alw = Al + (wid << 10);
  unsigned short* Blw = Bl + (wid << 10);

  f32x4 zero = {0.f, 0.f, 0.f, 0.f};
  f32x4 acc[4][4];
#pragma unroll
  for (int m = 0; m < 4; m++)
#pragma unroll
    for (int n = 0; n < 4; n++) acc[m][n] = zero;

  for (int kb = 0; kb < Dd; kb += 32) {
    __syncthreads();
    gload_lds16(Ag + kb, Alw);
    gload_lds16(Ag + kb + 16 * Dd, Alw + 16 * 32);
    gload_lds16(Bg + kb, Blw);
    gload_lds16(Bg + kb + 16 * Dd, Blw + 16 * 32);
    __syncthreads();
    bf16x8 af[4], bf[4];
#pragma unroll
    for (int m = 0; m < 4; m++)
      af[m] = *(const bf16x8*)(Al + (((wr << 6) + (m << 4) + lq) << 5) + (lh << 3));
#pragma unroll
    for (int n = 0; n < 4; n++)
      bf[n] = *(const bf16x8*)(Bl + (((wc << 6) + (n << 4) + lq) << 5) + (lh << 3));
#pragma unroll
    for (int m = 0; m < 4; m++)
#pragma unroll
      for (int n = 0; n < 4; n++) acc[m][n] = MFMA(af[m], bf[n], acc[m][n]);
  }

  int b_idx = mb >> 11;
#pragma unroll
  for (int n = 0; n < 4; n++) {
    int col = nb + (wc << 6) + (n << 4) + lq;
    float bb = bias[col];
    int hh = col >> 6, hd = col & 63;
#pragma unroll
    for (int m = 0; m < 4; m++) {
      int row0 = mb + (wr << 6) + (m << 4) + (lh << 2);
      int t0 = row0 & 2047;
      if (widx == 3) {
#pragma unroll
        for (int r = 0; r < 4; r++)
          Pout[(size_t)(row0 + r) * Dd + col] = acc[m][n][r] + bb;
      } else if (widx == 2) {
        float v0 = acc[m][n][0] + bb, v1 = acc[m][n][1] + bb;
        float v2 = acc[m][n][2] + bb, v3 = acc[m][n][3] + bb;
        uint2 pv;
        pv.x = f2b(v0) | ((uint32_t)f2b(v1) << 16);
        pv.y = f2b(v2) | ((uint32_t)f2b(v3) << 16);
        int t0s = t0 ^ ((hd & 7) << 3);  // V swizzle: t 16B-block ^= hd&7
        *(uint2*)(VTb + ((size_t)(b_idx * 16 + hh) * 64 + hd) * Tt + t0s) = pv;
      } else {
        unsigned short* O = (widx == 0) ? Qb : Kb;
        float sc = (widx == 0) ? (0.125f * LOG2E) : 1.0f;  // fold scale*log2e into Q
#pragma unroll
        for (int r = 0; r < 4; r++) {
          float v = (acc[m][n][r] + bb) * sc;
          int trow = t0 + r;
          int hds = (widx == 0) ? hd : (hd ^ ((trow & 7) << 3));  // K swizzle
          O[((size_t)(b_idx * 16 + hh) * Tt + trow) * 64 + hds] = f2b(v);
        }
      }
    }
  }
}

// ---------------- flash attention (causal), Q pre-scaled by 0.125*log2e ----------
// PERSISTENT work-queue version: 1280 blocks (5/CU capacity at 32KB LDS) grab
// (bh,qt) items from a global atomic counter in LPT order (heaviest qt first)
// until the 1024 items are exhausted -> dynamic load balance, no dispatch tail.
// Inner loop = r9 structure verbatim (2-buffer global_load_lds staging).
__global__ __launch_bounds__(256, 4) void k_attn(
    const unsigned short* __restrict__ Qb, const unsigned short* __restrict__ Kb,
    const unsigned short* __restrict__ VTb, unsigned short* __restrict__ yb) {
  __shared__ __align__(16) unsigned short KL[2][4096];
  __shared__ __align__(16) unsigned short VL[2][4096];
  __shared__ int s_item;
  int tid = threadIdx.x, lane = tid & 63, w = tid >> 6;
  int l31 = lane & 31, hi = lane >> 5;
  int srow = lane >> 3, scol = (lane & 7) << 3;
  int rowb = w << 4;           // wave stages 16 rows of K and of V per tile
  int swz = l31 & 7;

#define STAGE(kvt_, bi_) do {                                                       \
    int kv_ = (kvt_) << 6;                                                          \
    gload_lds16(Kh + (size_t)(kv_ + rowb + srow) * 64 + scol, &KL[bi_][rowb << 6]); \
    gload_lds16(Kh + (size_t)(kv_ + rowb + 8 + srow) * 64 + scol,                   \
                &KL[bi_][(rowb + 8) << 6]);                                         \
    gload_lds16(Vh + (size_t)(rowb + srow) * Tt + kv_ + scol, &VL[bi_][rowb << 6]); \
    gload_lds16(Vh + (size_t)(rowb + 8 + srow) * Tt + kv_ + scol,                   \
                &VL[bi_][(rowb + 8) << 6]);                                         \
  } while (0)

  for (;;) {
    if (tid == 0) s_item = atomicAdd(&g_ctr, 1);
    __syncthreads();   // publishes s_item; also fences prev item's LDS reads
    int item = s_item;
    if (item >= N_ITEMS) break;
    int qt = 15 - (item >> 6);       // heavy q-tiles grabbed first (LPT)
    int bh = item & 63;
    const unsigned short* __restrict__ Qh = Qb + (size_t)bh * Tt * 64;
    const unsigned short* __restrict__ Kh = Kb + (size_t)bh * Tt * 64;
    const unsigned short* __restrict__ Vh = VTb + (size_t)bh * 64 * Tt;
    int qg = (qt << 7) + (w << 5);   // wave's 32 q rows

    // Q B-fragments: lane holds Q[qg+l31][16c + 8hi + j]
    bf16x8 qf[4];
#pragma unroll
    for (int c = 0; c < 4; c++)
      qf[c] = *(const bf16x8*)(Qh + (size_t)(qg + l31) * 64 + (c << 4) + (hi << 3));

    f32x16 acc0, acc1;
#pragma unroll
    for (int i = 0; i < 16; i++) { acc0[i] = 0.f; acc1[i] = 0.f; }
    float lsum = 0.f;

    int jmax = (qt << 1) + 1;    // 64-row kv tiles: 0..jmax covers the q-tile diag

    // prologue: stage tile 0 into buf 0
    STAGE(0, 0);
    __syncthreads();

    int cur = 0;
    for (int jt = 0; jt <= jmax; ++jt) {
      if (jt < jmax) STAGE(jt + 1, cur ^ 1);  // latency hides under compute(jt)
      int kv0 = jt << 6;
      int d = qg - kv0;   // wave-uniform
      if (d >= 0) {
        const unsigned short* KB = &KL[cur][0];
        const unsigned short* VB = &VL[cur][0];
        bool diag = (d < 64);
        int rel = d + l31;
#pragma unroll
        for (int n2 = 0; n2 < 2; n2++) {
          // K fragments for this kv-half
          bf16x8 kf[4];
          int krowb = ((n2 << 5) + l31) << 6;
#pragma unroll
          for (int c = 0; c < 4; c++)
            kf[c] = *(const bf16x8*)(KB + krowb + ((((c << 1) + hi) ^ swz) << 3));
          f32x16 s;
#pragma unroll
          for (int i = 0; i < 16; i++) s[i] = 0.f;
          __builtin_amdgcn_s_setprio(1);
#pragma unroll
          for (int c = 0; c < 4; c++) s = MFMA32(kf[c], qf[c], s);
          __builtin_amdgcn_s_setprio(0);
          float p[16];
          if (diag) {
#pragma unroll
            for (int r = 0; r < 16; r++) {
              int krow = (n2 << 5) + (r & 3) + ((r >> 2) << 3) + (hi << 2);
              p[r] = EXP2(krow > rel ? -1e30f : s[r]);
            }
          } else {
#pragma unroll
            for (int r = 0; r < 16; r++) p[r] = EXP2(s[r]);
          }
          lsum += (((p[0] + p[1]) + (p[2] + p[3])) + ((p[4] + p[5]) + (p[6] + p[7])))
                + (((p[8] + p[9]) + (p[10] + p[11])) + ((p[12] + p[13]) + (p[14] + p[15])));
          // V fragments: element (hi,j) = V[kv0 + 32n2 + 16cc + 8(j>>2)+4hi+(j&3)][hd]
          union { uint2 u2[2]; bf16x8 v; } vf[2][2];
#pragma unroll
          for (int n2v = 0; n2v < 2; n2v++) {
            int vrowb = ((n2v << 5) + l31) << 6;
#pragma unroll
            for (int cc = 0; cc < 2; cc++) {
              int blk0 = (n2 << 2) + (cc << 1);
              vf[n2v][cc].u2[0] =
                  *(const uint2*)(VB + vrowb + ((blk0 ^ swz) << 3) + (hi << 2));
              vf[n2v][cc].u2[1] =
                  *(const uint2*)(VB + vrowb + (((blk0 + 1) ^ swz) << 3) + (hi << 2));
            }
          }
          // pack P into A-fragments (register-local; slot order matches V's b64 reads)
          union { uint32_t u[4]; bf16x8 v; } ap0, ap1;
#pragma unroll
          for (int g = 0; g < 4; g++) {
            ap0.u[g] = pk2(p[2 * g], p[2 * g + 1]);
            ap1.u[g] = pk2(p[8 + 2 * g], p[8 + 2 * g + 1]);
          }
          __builtin_amdgcn_s_setprio(1);
          acc0 = MFMA32(ap0.v, vf[0][0].v, acc0);
          acc1 = MFMA32(ap0.v, vf[1][0].v, acc1);
          acc0 = MFMA32(ap1.v, vf[0][1].v, acc0);
          acc1 = MFMA32(ap1.v, vf[1][1].v, acc1);
          __builtin_amdgcn_s_setprio(0);
        }
      }
      __syncthreads();
      cur ^= 1;
    }

    lsum += __shfl_xor(lsum, 32);
    float inv = 1.0f / lsum;
    int bb = bh >> 4, hh = bh & 15;
#pragma unroll
    for (int r = 0; r < 16; r++) {
      int qr = (r & 3) + ((r >> 2) << 3) + (hi << 2);
      float invq = __shfl(inv, qr);
      size_t base = ((size_t)(bb * Tt + qg + qr)) * Dd + (hh << 6) + l31;
      yb[base] = f2b(acc0[r] * invq);
      yb[base + 32] = f2b(acc1[r] * invq);
    }
  }
#undef STAGE
}

extern "C" void kernel_launch(void* const* d_in, const int* in_sizes, int n_in,
                              void* d_out, int out_size, void* d_ws, size_t ws_size,
                              hipStream_t stream) {
  const float* x = (const float*)d_in[0];
  const float* Wk = (const float*)d_in[1];
  const float* bk = (const float*)d_in[2];
  const float* Wq = (const float*)d_in[3];
  const float* bq = (const float*)d_in[4];
  const float* Wv = (const float*)d_in[5];
  const float* bv = (const float*)d_in[6];
  const float* Wp = (const float*)d_in[7];
  const float* bp = (const float*)d_in[8];
  float* out = (float*)d_out;

  char* ws = (char*)d_ws;
  unsigned short* xb  = (unsigned short*)(ws);                       // 16MB
  unsigned short* WkT = (unsigned short*)(ws + (16ull << 20));       // 2MB each
  unsigned short* WqT = (unsigned short*)(ws + (18ull << 20));
  unsigned short* WvT = (unsigned short*)(ws + (20ull << 20));
  unsigned short* WpT = (unsigned short*)(ws + (22ull << 20));
  unsigned short* Qb  = (unsigned short*)(ws + (24ull << 20));       // 16MB
  unsigned short* Kb  = (unsigned short*)(ws + (40ull << 20));       // 16MB
  unsigned short* VTb = (unsigned short*)(ws + (56ull << 20));       // 16MB
  unsigned short* yb  = (unsigned short*)(ws + (72ull << 20));       // 16MB (ends 88MB)

  k_convert_x<<<4096, 256, 0, stream>>>(x, xb);
  k_transpose_w<<<dim3(1024, 4), 256, 0, stream>>>(Wk, Wq, Wv, Wp, WkT, WqT, WvT, WpT);
  k_gemm<<<dim3(64, 24), 256, 0, stream>>>(xb, WqT, WkT, WvT, bq, bk, bv,
                                           Qb, Kb, VTb, nullptr, 1);
  k_attn<<<1280, 256, 0, stream>>>(Qb, Kb, VTb, yb);
  k_gemm<<<dim3(64, 8), 256, 0, stream>>>(yb, WpT, nullptr, nullptr, bp, nullptr, nullptr,
                                          nullptr, nullptr, nullptr, out, 0);
}

// Round 12
// 187.538 us; speedup vs baseline: 2.5716x; 1.0406x over previous
//
#include <hip/hip_runtime.h>
#include <stdint.h>

#define Bb 4
#define Tt 2048
#define Dd 1024
#define Hh 16
#define HDd 64
#define Mm 8192   // Bb*Tt

typedef __attribute__((ext_vector_type(8))) short bf16x8;
typedef __attribute__((ext_vector_type(4))) float f32x4;
typedef __attribute__((ext_vector_type(16))) float f32x16;

#define MFMA(a, b, c) __builtin_amdgcn_mfma_f32_16x16x32_bf16(a, b, c, 0, 0, 0)
#define MFMA32(a, b, c) __builtin_amdgcn_mfma_f32_32x32x16_bf16(a, b, c, 0, 0, 0)

#define LOG2E 1.44269504088896340736f
#if __has_builtin(__builtin_amdgcn_exp2f)
#define EXP2(x) __builtin_amdgcn_exp2f(x)
#else
#define EXP2(x) __expf((x) * 0.69314718055994530942f)
#endif

union vfu { uint2 u2[2]; bf16x8 v; };
union apu { uint32_t u[4]; bf16x8 v; };

__device__ __forceinline__ unsigned short f2b(float f) {
  union { float f; uint32_t u; } v; v.f = f;
  return (unsigned short)((v.u + 0x7FFFu + ((v.u >> 16) & 1u)) >> 16);
}

// pack two f32 -> bf16x2 (compiler emits v_cvt_pk_bf16_f32)
__device__ __forceinline__ uint32_t pk2(float a, float b) {
  union { __bf16 h[2]; uint32_t u; } x;
  x.h[0] = (__bf16)a; x.h[1] = (__bf16)b;
  return x.u;
}

__device__ __forceinline__ void gload_lds16(const void* g, void* l) {
  __builtin_amdgcn_global_load_lds(
      (const __attribute__((address_space(1))) void*)g,
      (__attribute__((address_space(3))) void*)l, 16, 0, 0);
}

// ---------------- x f32 -> bf16 ----------------
__global__ __launch_bounds__(256) void k_convert_x(const float* __restrict__ x,
                                                   unsigned short* __restrict__ xb) {
  int i = (blockIdx.x * 256 + threadIdx.x) * 8;
  float4 a = *(const float4*)(x + i);
  float4 b = *(const float4*)(x + i + 4);
  uint4 o;
  o.x = f2b(a.x) | ((uint32_t)f2b(a.y) << 16);
  o.y = f2b(a.z) | ((uint32_t)f2b(a.w) << 16);
  o.z = f2b(b.x) | ((uint32_t)f2b(b.y) << 16);
  o.w = f2b(b.z) | ((uint32_t)f2b(b.w) << 16);
  *(uint4*)(xb + i) = o;
}

// ---------------- W [K][N] f32 -> Wt [N][K] bf16 ----------------
__global__ __launch_bounds__(256) void k_transpose_w(
    const float* __restrict__ Wk, const float* __restrict__ Wq,
    const float* __restrict__ Wv, const float* __restrict__ Wp,
    unsigned short* __restrict__ WkT, unsigned short* __restrict__ WqT,
    unsigned short* __restrict__ WvT, unsigned short* __restrict__ WpT) {
  const float* W; unsigned short* O;
  int wsel = blockIdx.y;
  W = wsel == 0 ? Wk : wsel == 1 ? Wq : wsel == 2 ? Wv : Wp;
  O = wsel == 0 ? WkT : wsel == 1 ? WqT : wsel == 2 ? WvT : WpT;
  __shared__ unsigned short tile[32][36];
  int kb = (blockIdx.x >> 5) << 5;
  int nb = (blockIdx.x & 31) << 5;
  int t = threadIdx.x;
  int r = t >> 3, c4 = (t & 7) << 2;
  float4 v = *(const float4*)(W + (size_t)(kb + r) * Dd + nb + c4);
  tile[r][c4 + 0] = f2b(v.x); tile[r][c4 + 1] = f2b(v.y);
  tile[r][c4 + 2] = f2b(v.z); tile[r][c4 + 3] = f2b(v.w);
  __syncthreads();
  uint2 o;
  o.x = tile[c4 + 0][r] | ((uint32_t)tile[c4 + 1][r] << 16);
  o.y = tile[c4 + 2][r] | ((uint32_t)tile[c4 + 3][r] << 16);
  *(uint2*)(O + (size_t)(nb + r) * Dd + kb + c4) = o;
}

// ---------------- GEMM: A[M][1024] bf16 @ Bt[N][1024]^T + bias ----------------
// qkv=1: Q,K -> [B,H,T,64] (K row-swizzled, Q pre-scaled by 0.125*log2e),
//        V -> [B,H,64,T] (t-swizzled)
// qkv=0: f32 out [M][1024]
__global__ __launch_bounds__(256) void k_gemm(
    const unsigned short* __restrict__ A,
    const unsigned short* __restrict__ Bt0, const unsigned short* __restrict__ Bt1,
    const unsigned short* __restrict__ Bt2,
    const float* __restrict__ bias0, const float* __restrict__ bias1,
    const float* __restrict__ bias2,
    unsigned short* __restrict__ Qb, unsigned short* __restrict__ Kb,
    unsigned short* __restrict__ VTb, float* __restrict__ Pout, int qkv) {
  __shared__ __align__(16) unsigned short Al[128 * 32];
  __shared__ __align__(16) unsigned short Bl[128 * 32];
  int tid = threadIdx.x;
  int lane = tid & 63, wid = tid >> 6;
  int wr = wid >> 1, wc = wid & 1;
  int lq = lane & 15, lh = lane >> 4;
  int mb = blockIdx.x * 128;
  int by = blockIdx.y;
  int widx, nb;
  const unsigned short* Bt; const float* bias;
  if (qkv) {
    widx = by >> 3; nb = (by & 7) << 7;
    Bt = widx == 0 ? Bt0 : (widx == 1 ? Bt1 : Bt2);
    bias = widx == 0 ? bias0 : (widx == 1 ? bias1 : bias2);
  } else {
    widx = 3; nb = by << 7; Bt = Bt0; bias = bias0;
  }

  int srow = (wid << 5) + (lane >> 2);
  int scol = (lane & 3) << 3;
  const unsigned short* Ag = A + (size_t)(mb + srow) * Dd + scol;
  const unsigned short* Bg = Bt + (size_t)(nb + srow) * Dd + scol;
  unsigned short* Alw = Al + (wid << 10);
  unsigned short* Blw = Bl + (wid << 10);

  f32x4 zero = {0.f, 0.f, 0.f, 0.f};
  f32x4 acc[4][4];
#pragma unroll
  for (int m = 0; m < 4; m++)
#pragma unroll
    for (int n = 0; n < 4; n++) acc[m][n] = zero;

  for (int kb = 0; kb < Dd; kb += 32) {
    __syncthreads();
    gload_lds16(Ag + kb, Alw);
    gload_lds16(Ag + kb + 16 * Dd, Alw + 16 * 32);
    gload_lds16(Bg + kb, Blw);
    gload_lds16(Bg + kb + 16 * Dd, Blw + 16 * 32);
    __syncthreads();
    bf16x8 af[4], bf[4];
#pragma unroll
    for (int m = 0; m < 4; m++)
      af[m] = *(const bf16x8*)(Al + (((wr << 6) + (m << 4) + lq) << 5) + (lh << 3));
#pragma unroll
    for (int n = 0; n < 4; n++)
      bf[n] = *(const bf16x8*)(Bl + (((wc << 6) + (n << 4) + lq) << 5) + (lh << 3));
#pragma unroll
    for (int m = 0; m < 4; m++)
#pragma unroll
      for (int n = 0; n < 4; n++) acc[m][n] = MFMA(af[m], bf[n], acc[m][n]);
  }

  int b_idx = mb >> 11;
#pragma unroll
  for (int n = 0; n < 4; n++) {
    int col = nb + (wc << 6) + (n << 4) + lq;
    float bb = bias[col];
    int hh = col >> 6, hd = col & 63;
#pragma unroll
    for (int m = 0; m < 4; m++) {
      int row0 = mb + (wr << 6) + (m << 4) + (lh << 2);
      int t0 = row0 & 2047;
      if (widx == 3) {
#pragma unroll
        for (int r = 0; r < 4; r++)
          Pout[(size_t)(row0 + r) * Dd + col] = acc[m][n][r] + bb;
      } else if (widx == 2) {
        float v0 = acc[m][n][0] + bb, v1 = acc[m][n][1] + bb;
        float v2 = acc[m][n][2] + bb, v3 = acc[m][n][3] + bb;
        uint2 pv;
        pv.x = f2b(v0) | ((uint32_t)f2b(v1) << 16);
        pv.y = f2b(v2) | ((uint32_t)f2b(v3) << 16);
        int t0s = t0 ^ ((hd & 7) << 3);  // V swizzle: t 16B-block ^= hd&7
        *(uint2*)(VTb + ((size_t)(b_idx * 16 + hh) * 64 + hd) * Tt + t0s) = pv;
      } else {
        unsigned short* O = (widx == 0) ? Qb : Kb;
        float sc = (widx == 0) ? (0.125f * LOG2E) : 1.0f;  // fold scale*log2e into Q
#pragma unroll
        for (int r = 0; r < 4; r++) {
          float v = (acc[m][n][r] + bb) * sc;
          int trow = t0 + r;
          int hds = (widx == 0) ? hd : (hd ^ ((trow & 7) << 3));  // K swizzle
          O[((size_t)(b_idx * 16 + hh) * Tt + trow) * 64 + hds] = f2b(v);
        }
      }
    }
  }
}

// ---------------- flash attention (causal), Q pre-scaled by 0.125*log2e ----------
// 64 q-rows per wave (2 q-halves A/B): every staged KV tile, kf/vf LDS read,
// barrier and staging op is amortized over 2x MFMAs; 4 independent PV acc
// chains. Block = 4 waves x 64q = 256 q rows. Grid = 512 static:
// block b and b+256 share a CU with qt(b)+qt(b+256)=7 (balanced), bh keyed to
// XCD (b&7) so each XCD's L2 keeps 8 heads' KV.
__global__ __launch_bounds__(256, 2) void k_attn(
    const unsigned short* __restrict__ Qb, const unsigned short* __restrict__ Kb,
    const unsigned short* __restrict__ VTb, unsigned short* __restrict__ yb) {
  __shared__ __align__(16) unsigned short KL[2][4096];
  __shared__ __align__(16) unsigned short VL[2][4096];
  int b = blockIdx.x;
  int qt = (b < 256) ? (7 - (b >> 6)) : ((b - 256) >> 6);
  int rr6 = b & 63;
  int bh = ((rr6 & 7) << 3) | (rr6 >> 3);    // XCD x holds heads 8x..8x+7
  int tid = threadIdx.x, lane = tid & 63, w = tid >> 6;
  int l31 = lane & 31, hi = lane >> 5;
  const unsigned short* __restrict__ Qh = Qb + (size_t)bh * Tt * 64;
  const unsigned short* __restrict__ Kh = Kb + (size_t)bh * Tt * 64;
  const unsigned short* __restrict__ Vh = VTb + (size_t)bh * 64 * Tt;
  int qgA = (qt << 8) + (w << 6);            // wave's 64 q rows (two halves)
  int qgB = qgA + 32;

  // Q B-fragments for both halves: lane holds Q[qg+l31][16c + 8hi + j]
  bf16x8 qfA[4], qfB[4];
#pragma unroll
  for (int c = 0; c < 4; c++) {
    qfA[c] = *(const bf16x8*)(Qh + (size_t)(qgA + l31) * 64 + (c << 4) + (hi << 3));
    qfB[c] = *(const bf16x8*)(Qh + (size_t)(qgB + l31) * 64 + (c << 4) + (hi << 3));
  }

  f32x16 accA0, accA1, accB0, accB1;
#pragma unroll
  for (int i = 0; i < 16; i++) { accA0[i] = 0.f; accA1[i] = 0.f; accB0[i] = 0.f; accB1[i] = 0.f; }
  float lsumA = 0.f, lsumB = 0.f;

  int jmaxb = (qt << 2) + 3;   // block's last kv tile (wave 3 half-B diagonal)
  int srow = lane >> 3, scol = (lane & 7) << 3;
  int rowb = w << 4;           // wave stages 16 rows of K and of V per tile
  int swz = l31 & 7;

#define STAGE(kvt_, bi_) do {                                                       \
    int kv_ = (kvt_) << 6;                                                          \
    gload_lds16(Kh + (size_t)(kv_ + rowb + srow) * 64 + scol, &KL[bi_][rowb << 6]); \
    gload_lds16(Kh + (size_t)(kv_ + rowb + 8 + srow) * 64 + scol,                   \
                &KL[bi_][(rowb + 8) << 6]);                                         \
    gload_lds16(Vh + (size_t)(rowb + srow) * Tt + kv_ + scol, &VL[bi_][rowb << 6]); \
    gload_lds16(Vh + (size_t)(rowb + 8 + srow) * Tt + kv_ + scol,                   \
                &VL[bi_][(rowb + 8) << 6]);                                         \
  } while (0)

  // prologue: stage tile 0 into buf 0
  STAGE(0, 0);
  __syncthreads();

  int cur = 0;
  for (int jt = 0; jt <= jmaxb; ++jt) {
    if (jt < jmaxb) STAGE(jt + 1, cur ^ 1);  // latency hides under compute(jt)
    int kv0 = jt << 6;
    int dA = qgA - kv0;    // wave-uniform, multiple of 64
    if (dA >= 0) {
      const unsigned short* KB = &KL[cur][0];
      const unsigned short* VB = &VL[cur][0];
      bool dg = (dA == 0);   // wave's diagonal tile
      int relA = dA + l31, relB = relA + 32;
#pragma unroll
      for (int n2 = 0; n2 < 2; n2++) {
        // K fragments for this kv-half (shared by both q-halves)
        bf16x8 kf[4];
        int krowb = ((n2 << 5) + l31) << 6;
#pragma unroll
        for (int c = 0; c < 4; c++)
          kf[c] = *(const bf16x8*)(KB + krowb + ((((c << 1) + hi) ^ swz) << 3));
        f32x16 sA, sB;
#pragma unroll
        for (int i = 0; i < 16; i++) { sA[i] = 0.f; sB[i] = 0.f; }
        __builtin_amdgcn_s_setprio(1);
#pragma unroll
        for (int c = 0; c < 4; c++) {   // two independent QK chains
          sA = MFMA32(kf[c], qfA[c], sA);
          sB = MFMA32(kf[c], qfB[c], sB);
        }
        __builtin_amdgcn_s_setprio(0);
        float pA[16], pB[16];
        if (dg) {
#pragma unroll
          for (int r = 0; r < 16; r++) {
            int krow = (n2 << 5) + (r & 3) + ((r >> 2) << 3) + (hi << 2);
            pA[r] = EXP2(krow > relA ? -1e30f : sA[r]);
            pB[r] = EXP2(krow > relB ? -1e30f : sB[r]);
          }
        } else {
#pragma unroll
          for (int r = 0; r < 16; r++) { pA[r] = EXP2(sA[r]); pB[r] = EXP2(sB[r]); }
        }
        lsumA += (((pA[0] + pA[1]) + (pA[2] + pA[3])) + ((pA[4] + pA[5]) + (pA[6] + pA[7])))
               + (((pA[8] + pA[9]) + (pA[10] + pA[11])) + ((pA[12] + pA[13]) + (pA[14] + pA[15])));
        lsumB += (((pB[0] + pB[1]) + (pB[2] + pB[3])) + ((pB[4] + pB[5]) + (pB[6] + pB[7])))
               + (((pB[8] + pB[9]) + (pB[10] + pB[11])) + ((pB[12] + pB[13]) + (pB[14] + pB[15])));
        // V fragments (shared by both q-halves)
        vfu vf[2][2];
#pragma unroll
        for (int n2v = 0; n2v < 2; n2v++) {
          int vrowb = ((n2v << 5) + l31) << 6;
#pragma unroll
          for (int cc = 0; cc < 2; cc++) {
            int blk0 = (n2 << 2) + (cc << 1);
            vf[n2v][cc].u2[0] =
                *(const uint2*)(VB + vrowb + ((blk0 ^ swz) << 3) + (hi << 2));
            vf[n2v][cc].u2[1] =
                *(const uint2*)(VB + vrowb + (((blk0 + 1) ^ swz) << 3) + (hi << 2));
          }
        }
        // pack P into A-fragments (register-local)
        apu a0, a1, b0, b1;
#pragma unroll
        for (int g = 0; g < 4; g++) {
          a0.u[g] = pk2(pA[2 * g], pA[2 * g + 1]);
          a1.u[g] = pk2(pA[8 + 2 * g], pA[8 + 2 * g + 1]);
          b0.u[g] = pk2(pB[2 * g], pB[2 * g + 1]);
          b1.u[g] = pk2(pB[8 + 2 * g], pB[8 + 2 * g + 1]);
        }
        __builtin_amdgcn_s_setprio(1);
        accA0 = MFMA32(a0.v, vf[0][0].v, accA0);   // 4 independent acc chains
        accA1 = MFMA32(a0.v, vf[1][0].v, accA1);
        accB0 = MFMA32(b0.v, vf[0][0].v, accB0);
        accB1 = MFMA32(b0.v, vf[1][0].v, accB1);
        accA0 = MFMA32(a1.v, vf[0][1].v, accA0);
        accA1 = MFMA32(a1.v, vf[1][1].v, accA1);
        accB0 = MFMA32(b1.v, vf[0][1].v, accB0);
        accB1 = MFMA32(b1.v, vf[1][1].v, accB1);
        __builtin_amdgcn_s_setprio(0);
      }
    }
    __syncthreads();
    cur ^= 1;
  }
#undef STAGE

  lsumA += __shfl_xor(lsumA, 32);
  lsumB += __shfl_xor(lsumB, 32);
  float invA = 1.0f / lsumA;
  float invB = 1.0f / lsumB;
  int bb = bh >> 4, hh = bh & 15;
#pragma unroll
  for (int r = 0; r < 16; r++) {
    int qr = (r & 3) + ((r >> 2) << 3) + (hi << 2);
    float invqA = __shfl(invA, qr);
    float invqB = __shfl(invB, qr);
    size_t baseA = ((size_t)(bb * Tt + qgA + qr)) * Dd + (hh << 6) + l31;
    size_t baseB = ((size_t)(bb * Tt + qgB + qr)) * Dd + (hh << 6) + l31;
    yb[baseA] = f2b(accA0[r] * invqA);
    yb[baseA + 32] = f2b(accA1[r] * invqA);
    yb[baseB] = f2b(accB0[r] * invqB);
    yb[baseB + 32] = f2b(accB1[r] * invqB);
  }
}

extern "C" void kernel_launch(void* const* d_in, const int* in_sizes, int n_in,
                              void* d_out, int out_size, void* d_ws, size_t ws_size,
                              hipStream_t stream) {
  const float* x = (const float*)d_in[0];
  const float* Wk = (const float*)d_in[1];
  const float* bk = (const float*)d_in[2];
  const float* Wq = (const float*)d_in[3];
  const float* bq = (const float*)d_in[4];
  const float* Wv = (const float*)d_in[5];
  const float* bv = (const float*)d_in[6];
  const float* Wp = (const float*)d_in[7];
  const float* bp = (const float*)d_in[8];
  float* out = (float*)d_out;

  char* ws = (char*)d_ws;
  unsigned short* xb  = (unsigned short*)(ws);                       // 16MB
  unsigned short* WkT = (unsigned short*)(ws + (16ull << 20));       // 2MB each
  unsigned short* WqT = (unsigned short*)(ws + (18ull << 20));
  unsigned short* WvT = (unsigned short*)(ws + (20ull << 20));
  unsigned short* WpT = (unsigned short*)(ws + (22ull << 20));
  unsigned short* Qb  = (unsigned short*)(ws + (24ull << 20));       // 16MB
  unsigned short* Kb  = (unsigned short*)(ws + (40ull << 20));       // 16MB
  unsigned short* VTb = (unsigned short*)(ws + (56ull << 20));       // 16MB
  unsigned short* yb  = (unsigned short*)(ws + (72ull << 20));       // 16MB (ends 88MB)

  k_convert_x<<<4096, 256, 0, stream>>>(x, xb);
  k_transpose_w<<<dim3(1024, 4), 256, 0, stream>>>(Wk, Wq, Wv, Wp, WkT, WqT, WvT, WpT);
  k_gemm<<<dim3(64, 24), 256, 0, stream>>>(xb, WqT, WkT, WvT, bq, bk, bv,
                                           Qb, Kb, VTb, nullptr, 1);
  k_attn<<<512, 256, 0, stream>>>(Qb, Kb, VTb, yb);
  k_gemm<<<dim3(64, 8), 256, 0, stream>>>(yb, WpT, nullptr, nullptr, bp, nullptr, nullptr,
                                          nullptr, nullptr, nullptr, out, 0);
}

// Round 13
// 165.461 us; speedup vs baseline: 2.9147x; 1.1334x over previous
//
#include <hip/hip_runtime.h>
#include <stdint.h>

#define Bb 4
#define Tt 2048
#define Dd 1024
#define Hh 16
#define HDd 64
#define Mm 8192   // Bb*Tt

typedef __attribute__((ext_vector_type(8))) short bf16x8;
typedef __attribute__((ext_vector_type(4))) float f32x4;
typedef __attribute__((ext_vector_type(16))) float f32x16;

#define MFMA(a, b, c) __builtin_amdgcn_mfma_f32_16x16x32_bf16(a, b, c, 0, 0, 0)
#define MFMA32(a, b, c) __builtin_amdgcn_mfma_f32_32x32x16_bf16(a, b, c, 0, 0, 0)

#define LOG2E 1.44269504088896340736f
#if __has_builtin(__builtin_amdgcn_exp2f)
#define EXP2(x) __builtin_amdgcn_exp2f(x)
#else
#define EXP2(x) __expf((x) * 0.69314718055994530942f)
#endif

union vfu { uint2 u2[2]; bf16x8 v; };
union apu { uint32_t u[4]; bf16x8 v; };

__device__ __forceinline__ unsigned short f2b(float f) {
  union { float f; uint32_t u; } v; v.f = f;
  return (unsigned short)((v.u + 0x7FFFu + ((v.u >> 16) & 1u)) >> 16);
}

// pack two f32 -> bf16x2 (compiler emits v_cvt_pk_bf16_f32)
__device__ __forceinline__ uint32_t pk2(float a, float b) {
  union { __bf16 h[2]; uint32_t u; } x;
  x.h[0] = (__bf16)a; x.h[1] = (__bf16)b;
  return x.u;
}

__device__ __forceinline__ void gload_lds16(const void* g, void* l) {
  __builtin_amdgcn_global_load_lds(
      (const __attribute__((address_space(1))) void*)g,
      (__attribute__((address_space(3))) void*)l, 16, 0, 0);
}

// ---------------- x f32 -> bf16 ----------------
__global__ __launch_bounds__(256) void k_convert_x(const float* __restrict__ x,
                                                   unsigned short* __restrict__ xb) {
  int i = (blockIdx.x * 256 + threadIdx.x) * 8;
  float4 a = *(const float4*)(x + i);
  float4 b = *(const float4*)(x + i + 4);
  uint4 o;
  o.x = f2b(a.x) | ((uint32_t)f2b(a.y) << 16);
  o.y = f2b(a.z) | ((uint32_t)f2b(a.w) << 16);
  o.z = f2b(b.x) | ((uint32_t)f2b(b.y) << 16);
  o.w = f2b(b.z) | ((uint32_t)f2b(b.w) << 16);
  *(uint4*)(xb + i) = o;
}

// ---------------- W [K][N] f32 -> Wt [N][K] bf16 ----------------
__global__ __launch_bounds__(256) void k_transpose_w(
    const float* __restrict__ Wk, const float* __restrict__ Wq,
    const float* __restrict__ Wv, const float* __restrict__ Wp,
    unsigned short* __restrict__ WkT, unsigned short* __restrict__ WqT,
    unsigned short* __restrict__ WvT, unsigned short* __restrict__ WpT) {
  const float* W; unsigned short* O;
  int wsel = blockIdx.y;
  W = wsel == 0 ? Wk : wsel == 1 ? Wq : wsel == 2 ? Wv : Wp;
  O = wsel == 0 ? WkT : wsel == 1 ? WqT : wsel == 2 ? WvT : WpT;
  __shared__ unsigned short tile[32][36];
  int kb = (blockIdx.x >> 5) << 5;
  int nb = (blockIdx.x & 31) << 5;
  int t = threadIdx.x;
  int r = t >> 3, c4 = (t & 7) << 2;
  float4 v = *(const float4*)(W + (size_t)(kb + r) * Dd + nb + c4);
  tile[r][c4 + 0] = f2b(v.x); tile[r][c4 + 1] = f2b(v.y);
  tile[r][c4 + 2] = f2b(v.z); tile[r][c4 + 3] = f2b(v.w);
  __syncthreads();
  uint2 o;
  o.x = tile[c4 + 0][r] | ((uint32_t)tile[c4 + 1][r] << 16);
  o.y = tile[c4 + 2][r] | ((uint32_t)tile[c4 + 3][r] << 16);
  *(uint2*)(O + (size_t)(nb + r) * Dd + kb + c4) = o;
}

// ---------------- fused QKV GEMM: xb @ {Wq,Wk,Wv}^T + bias ----------------
// One block computes a 128x128 output slice of Q, K AND V: A staged once per
// K-step, 3 B tiles, 48 MFMA/wave/K-step (3x arithmetic per barrier-drain).
// Epilogues identical to the validated k_gemm widx paths:
//   Q -> [B,H,T,64] scaled by 0.125*log2e; K -> row-swizzled; V -> [B,H,64,T]
//   t-swizzled.
__global__ __launch_bounds__(256, 2) void k_gemm3(
    const unsigned short* __restrict__ A,
    const unsigned short* __restrict__ BtQ, const unsigned short* __restrict__ BtK,
    const unsigned short* __restrict__ BtV,
    const float* __restrict__ bq, const float* __restrict__ bk,
    const float* __restrict__ bv,
    unsigned short* __restrict__ Qb, unsigned short* __restrict__ Kb,
    unsigned short* __restrict__ VTb) {
  __shared__ __align__(16) unsigned short Al[128 * 32];
  __shared__ __align__(16) unsigned short Bl[3][128 * 32];
  int tid = threadIdx.x;
  int lane = tid & 63, wid = tid >> 6;
  int wr = wid >> 1, wc = wid & 1;
  int lq = lane & 15, lh = lane >> 4;
  int mb = blockIdx.x * 128;
  int nb = blockIdx.y << 7;

  int srow = (wid << 5) + (lane >> 2);
  int scol = (lane & 3) << 3;
  const unsigned short* Ag = A + (size_t)(mb + srow) * Dd + scol;
  const unsigned short* Bg0 = BtQ + (size_t)(nb + srow) * Dd + scol;
  const unsigned short* Bg1 = BtK + (size_t)(nb + srow) * Dd + scol;
  const unsigned short* Bg2 = BtV + (size_t)(nb + srow) * Dd + scol;
  unsigned short* Alw = Al + (wid << 10);   // wave-uniform LDS bases
  unsigned short* Blw0 = &Bl[0][0] + (wid << 10);
  unsigned short* Blw1 = &Bl[1][0] + (wid << 10);
  unsigned short* Blw2 = &Bl[2][0] + (wid << 10);

  f32x4 zero = {0.f, 0.f, 0.f, 0.f};
  f32x4 acc[3][4][4];
#pragma unroll
  for (int s = 0; s < 3; s++)
#pragma unroll
    for (int m = 0; m < 4; m++)
#pragma unroll
      for (int n = 0; n < 4; n++) acc[s][m][n] = zero;

  for (int kb = 0; kb < Dd; kb += 32) {
    __syncthreads();
    gload_lds16(Ag + kb, Alw);
    gload_lds16(Ag + kb + 16 * Dd, Alw + 16 * 32);
    gload_lds16(Bg0 + kb, Blw0);
    gload_lds16(Bg0 + kb + 16 * Dd, Blw0 + 16 * 32);
    gload_lds16(Bg1 + kb, Blw1);
    gload_lds16(Bg1 + kb + 16 * Dd, Blw1 + 16 * 32);
    gload_lds16(Bg2 + kb, Blw2);
    gload_lds16(Bg2 + kb + 16 * Dd, Blw2 + 16 * 32);
    __syncthreads();
    bf16x8 af[4];
#pragma unroll
    for (int m = 0; m < 4; m++)
      af[m] = *(const bf16x8*)(Al + (((wr << 6) + (m << 4) + lq) << 5) + (lh << 3));
#pragma unroll
    for (int s = 0; s < 3; s++) {
      bf16x8 bf[4];
#pragma unroll
      for (int n = 0; n < 4; n++)
        bf[n] = *(const bf16x8*)(&Bl[s][0] +
                                 (((wc << 6) + (n << 4) + lq) << 5) + (lh << 3));
      __builtin_amdgcn_s_setprio(1);
#pragma unroll
      for (int m = 0; m < 4; m++)
#pragma unroll
        for (int n = 0; n < 4; n++) acc[s][m][n] = MFMA(af[m], bf[n], acc[s][m][n]);
      __builtin_amdgcn_s_setprio(0);
    }
  }

  int b_idx = mb >> 11;  // batch index (128-row tile never crosses T)
#pragma unroll
  for (int s = 0; s < 3; s++) {
#pragma unroll
    for (int n = 0; n < 4; n++) {
      int col = nb + (wc << 6) + (n << 4) + lq;
      float bbias = (s == 0) ? bq[col] : (s == 1) ? bk[col] : bv[col];
      int hh = col >> 6, hd = col & 63;
#pragma unroll
      for (int m = 0; m < 4; m++) {
        int row0 = mb + (wr << 6) + (m << 4) + (lh << 2);
        int t0 = row0 & 2047;
        if (s == 2) {          // V -> [B,H,64,T], t-swizzled
          float v0 = acc[s][m][n][0] + bbias, v1 = acc[s][m][n][1] + bbias;
          float v2 = acc[s][m][n][2] + bbias, v3 = acc[s][m][n][3] + bbias;
          uint2 pv;
          pv.x = f2b(v0) | ((uint32_t)f2b(v1) << 16);
          pv.y = f2b(v2) | ((uint32_t)f2b(v3) << 16);
          int t0s = t0 ^ ((hd & 7) << 3);
          *(uint2*)(VTb + ((size_t)(b_idx * 16 + hh) * 64 + hd) * Tt + t0s) = pv;
        } else {               // Q (scaled) / K (row-swizzled) -> [B,H,T,64]
          unsigned short* O = (s == 0) ? Qb : Kb;
          float sc = (s == 0) ? (0.125f * LOG2E) : 1.0f;
#pragma unroll
          for (int r = 0; r < 4; r++) {
            float v = (acc[s][m][n][r] + bbias) * sc;
            int trow = t0 + r;
            int hds = (s == 0) ? hd : (hd ^ ((trow & 7) << 3));
            O[((size_t)(b_idx * 16 + hh) * Tt + trow) * 64 + hds] = f2b(v);
          }
        }
      }
    }
  }
}

// ---------------- GEMM (projection): A[M][1024] bf16 @ Bt^T + bias -> f32 ----
__global__ __launch_bounds__(256) void k_gemm(
    const unsigned short* __restrict__ A,
    const unsigned short* __restrict__ Bt0,
    const float* __restrict__ bias0,
    float* __restrict__ Pout) {
  __shared__ __align__(16) unsigned short Al[128 * 32];
  __shared__ __align__(16) unsigned short Bl[128 * 32];
  int tid = threadIdx.x;
  int lane = tid & 63, wid = tid >> 6;
  int wr = wid >> 1, wc = wid & 1;
  int lq = lane & 15, lh = lane >> 4;
  int mb = blockIdx.x * 128;
  int nb = blockIdx.y << 7;
  const unsigned short* Bt = Bt0; const float* bias = bias0;

  int srow = (wid << 5) + (lane >> 2);
  int scol = (lane & 3) << 3;
  const unsigned short* Ag = A + (size_t)(mb + srow) * Dd + scol;
  const unsigned short* Bg = Bt + (size_t)(nb + srow) * Dd + scol;
  unsigned short* Alw = Al + (wid << 10);
  unsigned short* Blw = Bl + (wid << 10);

  f32x4 zero = {0.f, 0.f, 0.f, 0.f};
  f32x4 acc[4][4];
#pragma unroll
  for (int m = 0; m < 4; m++)
#pragma unroll
    for (int n = 0; n < 4; n++) acc[m][n] = zero;

  for (int kb = 0; kb < Dd; kb += 32) {
    __syncthreads();
    gload_lds16(Ag + kb, Alw);
    gload_lds16(Ag + kb + 16 * Dd, Alw + 16 * 32);
    gload_lds16(Bg + kb, Blw);
    gload_lds16(Bg + kb + 16 * Dd, Blw + 16 * 32);
    __syncthreads();
    bf16x8 af[4], bf[4];
#pragma unroll
    for (int m = 0; m < 4; m++)
      af[m] = *(const bf16x8*)(Al + (((wr << 6) + (m << 4) + lq) << 5) + (lh << 3));
#pragma unroll
    for (int n = 0; n < 4; n++)
      bf[n] = *(const bf16x8*)(Bl + (((wc << 6) + (n << 4) + lq) << 5) + (lh << 3));
#pragma unroll
    for (int m = 0; m < 4; m++)
#pragma unroll
      for (int n = 0; n < 4; n++) acc[m][n] = MFMA(af[m], bf[n], acc[m][n]);
  }

#pragma unroll
  for (int n = 0; n < 4; n++) {
    int col = nb + (wc << 6) + (n << 4) + lq;
    float bb = bias[col];
#pragma unroll
    for (int m = 0; m < 4; m++) {
      int row0 = mb + (wr << 6) + (m << 4) + (lh << 2);
#pragma unroll
      for (int r = 0; r < 4; r++)
        Pout[(size_t)(row0 + r) * Dd + col] = acc[m][n][r] + bb;
    }
  }
}

// ---------------- flash attention (causal), Q pre-scaled by 0.125*log2e ----------
// 64 q-rows per wave (2 q-halves A/B); staged KV shared across both halves.
// Block = 4 waves x 64q = 256 q rows. Grid 512, complement-paired qt for CU
// balance, bh keyed to XCD for L2 locality. (r12 kernel, unchanged.)
__global__ __launch_bounds__(256, 2) void k_attn(
    const unsigned short* __restrict__ Qb, const unsigned short* __restrict__ Kb,
    const unsigned short* __restrict__ VTb, unsigned short* __restrict__ yb) {
  __shared__ __align__(16) unsigned short KL[2][4096];
  __shared__ __align__(16) unsigned short VL[2][4096];
  int b = blockIdx.x;
  int qt = (b < 256) ? (7 - (b >> 6)) : ((b - 256) >> 6);
  int rr6 = b & 63;
  int bh = ((rr6 & 7) << 3) | (rr6 >> 3);    // XCD x holds heads 8x..8x+7
  int tid = threadIdx.x, lane = tid & 63, w = tid >> 6;
  int l31 = lane & 31, hi = lane >> 5;
  const unsigned short* __restrict__ Qh = Qb + (size_t)bh * Tt * 64;
  const unsigned short* __restrict__ Kh = Kb + (size_t)bh * Tt * 64;
  const unsigned short* __restrict__ Vh = VTb + (size_t)bh * 64 * Tt;
  int qgA = (qt << 8) + (w << 6);            // wave's 64 q rows (two halves)
  int qgB = qgA + 32;

  bf16x8 qfA[4], qfB[4];
#pragma unroll
  for (int c = 0; c < 4; c++) {
    qfA[c] = *(const bf16x8*)(Qh + (size_t)(qgA + l31) * 64 + (c << 4) + (hi << 3));
    qfB[c] = *(const bf16x8*)(Qh + (size_t)(qgB + l31) * 64 + (c << 4) + (hi << 3));
  }

  f32x16 accA0, accA1, accB0, accB1;
#pragma unroll
  for (int i = 0; i < 16; i++) { accA0[i] = 0.f; accA1[i] = 0.f; accB0[i] = 0.f; accB1[i] = 0.f; }
  float lsumA = 0.f, lsumB = 0.f;

  int jmaxb = (qt << 2) + 3;
  int srow = lane >> 3, scol = (lane & 7) << 3;
  int rowb = w << 4;
  int swz = l31 & 7;

#define STAGE(kvt_, bi_) do {                                                       \
    int kv_ = (kvt_) << 6;                                                          \
    gload_lds16(Kh + (size_t)(kv_ + rowb + srow) * 64 + scol, &KL[bi_][rowb << 6]); \
    gload_lds16(Kh + (size_t)(kv_ + rowb + 8 + srow) * 64 + scol,                   \
                &KL[bi_][(rowb + 8) << 6]);                                         \
    gload_lds16(Vh + (size_t)(rowb + srow) * Tt + kv_ + scol, &VL[bi_][rowb << 6]); \
    gload_lds16(Vh + (size_t)(rowb + 8 + srow) * Tt + kv_ + scol,                   \
                &VL[bi_][(rowb + 8) << 6]);                                         \
  } while (0)

  STAGE(0, 0);
  __syncthreads();

  int cur = 0;
  for (int jt = 0; jt <= jmaxb; ++jt) {
    if (jt < jmaxb) STAGE(jt + 1, cur ^ 1);
    int kv0 = jt << 6;
    int dA = qgA - kv0;
    if (dA >= 0) {
      const unsigned short* KB = &KL[cur][0];
      const unsigned short* VB = &VL[cur][0];
      bool dg = (dA == 0);
      int relA = dA + l31, relB = relA + 32;
#pragma unroll
      for (int n2 = 0; n2 < 2; n2++) {
        bf16x8 kf[4];
        int krowb = ((n2 << 5) + l31) << 6;
#pragma unroll
        for (int c = 0; c < 4; c++)
          kf[c] = *(const bf16x8*)(KB + krowb + ((((c << 1) + hi) ^ swz) << 3));
        f32x16 sA, sB;
#pragma unroll
        for (int i = 0; i < 16; i++) { sA[i] = 0.f; sB[i] = 0.f; }
        __builtin_amdgcn_s_setprio(1);
#pragma unroll
        for (int c = 0; c < 4; c++) {
          sA = MFMA32(kf[c], qfA[c], sA);
          sB = MFMA32(kf[c], qfB[c], sB);
        }
        __builtin_amdgcn_s_setprio(0);
        float pA[16], pB[16];
        if (dg) {
#pragma unroll
          for (int r = 0; r < 16; r++) {
            int krow = (n2 << 5) + (r & 3) + ((r >> 2) << 3) + (hi << 2);
            pA[r] = EXP2(krow > relA ? -1e30f : sA[r]);
            pB[r] = EXP2(krow > relB ? -1e30f : sB[r]);
          }
        } else {
#pragma unroll
          for (int r = 0; r < 16; r++) { pA[r] = EXP2(sA[r]); pB[r] = EXP2(sB[r]); }
        }
        lsumA += (((pA[0] + pA[1]) + (pA[2] + pA[3])) + ((pA[4] + pA[5]) + (pA[6] + pA[7])))
               + (((pA[8] + pA[9]) + (pA[10] + pA[11])) + ((pA[12] + pA[13]) + (pA[14] + pA[15])));
        lsumB += (((pB[0] + pB[1]) + (pB[2] + pB[3])) + ((pB[4] + pB[5]) + (pB[6] + pB[7])))
               + (((pB[8] + pB[9]) + (pB[10] + pB[11])) + ((pB[12] + pB[13]) + (pB[14] + pB[15])));
        vfu vf[2][2];
#pragma unroll
        for (int n2v = 0; n2v < 2; n2v++) {
          int vrowb = ((n2v << 5) + l31) << 6;
#pragma unroll
          for (int cc = 0; cc < 2; cc++) {
            int blk0 = (n2 << 2) + (cc << 1);
            vf[n2v][cc].u2[0] =
                *(const uint2*)(VB + vrowb + ((blk0 ^ swz) << 3) + (hi << 2));
            vf[n2v][cc].u2[1] =
                *(const uint2*)(VB + vrowb + (((blk0 + 1) ^ swz) << 3) + (hi << 2));
          }
        }
        apu a0, a1, b0, b1;
#pragma unroll
        for (int g = 0; g < 4; g++) {
          a0.u[g] = pk2(pA[2 * g], pA[2 * g + 1]);
          a1.u[g] = pk2(pA[8 + 2 * g], pA[8 + 2 * g + 1]);
          b0.u[g] = pk2(pB[2 * g], pB[2 * g + 1]);
          b1.u[g] = pk2(pB[8 + 2 * g], pB[8 + 2 * g + 1]);
        }
        __builtin_amdgcn_s_setprio(1);
        accA0 = MFMA32(a0.v, vf[0][0].v, accA0);
        accA1 = MFMA32(a0.v, vf[1][0].v, accA1);
        accB0 = MFMA32(b0.v, vf[0][0].v, accB0);
        accB1 = MFMA32(b0.v, vf[1][0].v, accB1);
        accA0 = MFMA32(a1.v, vf[0][1].v, accA0);
        accA1 = MFMA32(a1.v, vf[1][1].v, accA1);
        accB0 = MFMA32(b1.v, vf[0][1].v, accB0);
        accB1 = MFMA32(b1.v, vf[1][1].v, accB1);
        __builtin_amdgcn_s_setprio(0);
      }
    }
    __syncthreads();
    cur ^= 1;
  }
#undef STAGE

  lsumA += __shfl_xor(lsumA, 32);
  lsumB += __shfl_xor(lsumB, 32);
  float invA = 1.0f / lsumA;
  float invB = 1.0f / lsumB;
  int bb = bh >> 4, hh = bh & 15;
#pragma unroll
  for (int r = 0; r < 16; r++) {
    int qr = (r & 3) + ((r >> 2) << 3) + (hi << 2);
    float invqA = __shfl(invA, qr);
    float invqB = __shfl(invB, qr);
    size_t baseA = ((size_t)(bb * Tt + qgA + qr)) * Dd + (hh << 6) + l31;
    size_t baseB = ((size_t)(bb * Tt + qgB + qr)) * Dd + (hh << 6) + l31;
    yb[baseA] = f2b(accA0[r] * invqA);
    yb[baseA + 32] = f2b(accA1[r] * invqA);
    yb[baseB] = f2b(accB0[r] * invqB);
    yb[baseB + 32] = f2b(accB1[r] * invqB);
  }
}

extern "C" void kernel_launch(void* const* d_in, const int* in_sizes, int n_in,
                              void* d_out, int out_size, void* d_ws, size_t ws_size,
                              hipStream_t stream) {
  const float* x = (const float*)d_in[0];
  const float* Wk = (const float*)d_in[1];
  const float* bk = (const float*)d_in[2];
  const float* Wq = (const float*)d_in[3];
  const float* bq = (const float*)d_in[4];
  const float* Wv = (const float*)d_in[5];
  const float* bv = (const float*)d_in[6];
  const float* Wp = (const float*)d_in[7];
  const float* bp = (const float*)d_in[8];
  float* out = (float*)d_out;

  char* ws = (char*)d_ws;
  unsigned short* xb  = (unsigned short*)(ws);                       // 16MB
  unsigned short* WkT = (unsigned short*)(ws + (16ull << 20));       // 2MB each
  unsigned short* WqT = (unsigned short*)(ws + (18ull << 20));
  unsigned short* WvT = (unsigned short*)(ws + (20ull << 20));
  unsigned short* WpT = (unsigned short*)(ws + (22ull << 20));
  unsigned short* Qb  = (unsigned short*)(ws + (24ull << 20));       // 16MB
  unsigned short* Kb  = (unsigned short*)(ws + (40ull << 20));       // 16MB
  unsigned short* VTb = (unsigned short*)(ws + (56ull << 20));       // 16MB
  unsigned short* yb  = (unsigned short*)(ws + (72ull << 20));       // 16MB (ends 88MB)

  k_convert_x<<<4096, 256, 0, stream>>>(x, xb);
  k_transpose_w<<<dim3(1024, 4), 256, 0, stream>>>(Wk, Wq, Wv, Wp, WkT, WqT, WvT, WpT);
  k_gemm3<<<dim3(64, 8), 256, 0, stream>>>(xb, WqT, WkT, WvT, bq, bk, bv,
                                           Qb, Kb, VTb);
  k_attn<<<512, 256, 0, stream>>>(Qb, Kb, VTb, yb);
  k_gemm<<<dim3(64, 8), 256, 0, stream>>>(yb, WpT, bp, out);
}